// Round 1
// baseline (675.690 us; speedup 1.0000x reference)
//
#include <hip/hip_runtime.h>
#include <math.h>

#define NB 8
#define HH 64
#define WW 64
#define C 192
#define G 12
#define GC 16
#define P 9
#define NPIX (NB*HH*WW)
#define PPB 8

// ---------------- K1/K4: per-pixel projection  out = in @ W(CxC) + b ----------------
__global__ __launch_bounds__(192) void proj_kernel(const float* __restrict__ in,
    const float* __restrict__ Wm, const float* __restrict__ bias,
    float* __restrict__ out) {
  __shared__ float xs[PPB][C];
  int pix0 = blockIdx.x * PPB;
  for (int i = threadIdx.x; i < PPB*C; i += 192)
    xs[i/C][i%C] = in[(size_t)pix0*C + i];
  __syncthreads();
  int c = threadIdx.x;
  float b = bias[c];
  float acc[PPB];
  #pragma unroll
  for (int p=0;p<PPB;p++) acc[p]=b;
  for (int k=0;k<C;k++){
    float wv = Wm[k*C + c];
    #pragma unroll
    for (int p=0;p<PPB;p++) acc[p] += xs[p][k]*wv;
  }
  // all global reads of `in` finished at the first barrier -> safe if out==in
  #pragma unroll
  for (int p=0;p<PPB;p++)
    out[((size_t)(pix0+p))*C + c] = acc[p];
}

// ---------------- K2: depthwise 5x5 + LayerNorm + exact GELU -> u ----------------
__global__ __launch_bounds__(192) void dw_ln_gelu_kernel(const float* __restrict__ x,
    const float* __restrict__ dw_w, const float* __restrict__ dw_b,
    const float* __restrict__ ln_g, const float* __restrict__ ln_b,
    float* __restrict__ u_out) {
  int pix = blockIdx.x;
  int n = pix / (HH*WW); int hw = pix % (HH*WW); int h = hw / WW; int w = hw % WW;
  int c = threadIdx.x;
  float acc = dw_b[c];
  #pragma unroll
  for (int i=0;i<5;i++){
    int hy = h + i - 2;
    if (hy < 0 || hy >= HH) continue;
    #pragma unroll
    for (int j=0;j<5;j++){
      int wx = w + j - 2;
      if (wx < 0 || wx >= WW) continue;
      acc += x[(((size_t)n*HH + hy)*WW + wx)*C + c] * dw_w[(i*5+j)*C + c];
    }
  }
  // block-wide mean/var over 192 channels (3 waves)
  float v1 = acc, v2 = acc*acc;
  #pragma unroll
  for (int o=32;o>0;o>>=1){ v1 += __shfl_down(v1,o); v2 += __shfl_down(v2,o); }
  __shared__ float s1[3], s2[3];
  __shared__ float mu_s, rstd_s;
  int wid = threadIdx.x >> 6, lane = threadIdx.x & 63;
  if (lane==0){ s1[wid]=v1; s2[wid]=v2; }
  __syncthreads();
  if (threadIdx.x==0){
    float t1 = s1[0]+s1[1]+s1[2];
    float t2 = s2[0]+s2[1]+s2[2];
    float mu = t1/(float)C;
    float var = t2/(float)C - mu*mu;
    mu_s = mu; rstd_s = rsqrtf(var + 1e-5f);
  }
  __syncthreads();
  float uv = (acc - mu_s)*rstd_s*ln_g[c] + ln_b[c];
  uv = 0.5f*uv*(1.0f + erff(uv*0.70710678118654752f));  // exact GELU
  u_out[(size_t)pix*C + c] = uv;
}

// ---------------- K3: offset/mask/cfs projection + DCNv3 sampling + gated blend ----------------
__global__ __launch_bounds__(192) void dcn_kernel(const float* __restrict__ u,
    const float* __restrict__ x_proj,
    const float* __restrict__ off_w, const float* __restrict__ off_b,
    const float* __restrict__ msk_w, const float* __restrict__ msk_b,
    const float* __restrict__ cfs_w, const float* __restrict__ cfs_b,
    float* __restrict__ y_out) {
  int pix = blockIdx.x;
  int n = pix / (HH*WW); int hw = pix % (HH*WW); int h = hw / WW; int w = hw % WW;
  int tid = threadIdx.x;
  __shared__ float us[C];
  __shared__ float offs[G*P*2];   // 216: [(g*9+p)*2 + {x,y}]
  __shared__ float msk[G*P];      // 108
  __shared__ float cfs[G];        // 12
  us[tid] = u[(size_t)pix*C + tid];
  __syncthreads();
  // 336 outputs = 216 offset + 108 mask + 12 cfs
  for (int o = tid; o < 336; o += 192) {
    float a; const float* Wp; int col, stride;
    if (o < 216)      { Wp = off_w; col = o;     stride = 216; a = off_b[col]; }
    else if (o < 324) { Wp = msk_w; col = o-216; stride = 108; a = msk_b[col]; }
    else              { Wp = cfs_w; col = o-324; stride = 12;  a = cfs_b[col]; }
    for (int k=0;k<C;k++) a += us[k]*Wp[k*stride+col];
    if (o < 216) offs[o]=a; else if (o < 324) msk[o-216]=a; else cfs[o-324]=a;
  }
  __syncthreads();
  if (tid < G) {
    float m = -1e30f;
    #pragma unroll
    for (int p=0;p<P;p++) m = fmaxf(m, msk[tid*P+p]);
    float e[P]; float s = 0.f;
    #pragma unroll
    for (int p=0;p<P;p++){ e[p] = expf(msk[tid*P+p]-m); s += e[p]; }
    float inv = 1.0f/s;
    #pragma unroll
    for (int p=0;p<P;p++) msk[tid*P+p] = e[p]*inv;
    cfs[tid] = 1.0f/(1.0f+expf(-cfs[tid]));   // sigmoid
  }
  __syncthreads();
  int c = tid, g = c >> 4;
  const float pts[3] = {-1.f, 0.f, 1.f};
  size_t baseN = (size_t)n*HH*WW*C;
  float accY = 0.f;
  #pragma unroll
  for (int p=0;p<P;p++){
    float ox = offs[2*(g*P+p)], oy = offs[2*(g*P+p)+1];
    float gx = 1.0f + (float)w + pts[p/3] + ox;   // padded-image coords (66x66)
    float gy = 1.0f + (float)h + pts[p%3] + oy;
    float x0f = floorf(gx), y0f = floorf(gy);
    float wx1 = gx - x0f, wy1 = gy - y0f;
    float wx0 = 1.f-wx1, wy0 = 1.f-wy1;
    int x0 = (int)x0f, y0 = (int)y0f;
    bool xv0 = (x0   >= 1) && (x0   <= 64);
    bool xv1 = (x0+1 >= 1) && (x0+1 <= 64);
    bool yv0 = (y0   >= 1) && (y0   <= 64);
    bool yv1 = (y0+1 >= 1) && (y0+1 <= 64);
    float v00 = (yv0 && xv0) ? x_proj[baseN + ((size_t)(y0-1)*WW + (x0-1))*C + c] : 0.f;
    float v01 = (yv0 && xv1) ? x_proj[baseN + ((size_t)(y0-1)*WW + (x0  ))*C + c] : 0.f;
    float v10 = (yv1 && xv0) ? x_proj[baseN + ((size_t)(y0  )*WW + (x0-1))*C + c] : 0.f;
    float v11 = (yv1 && xv1) ? x_proj[baseN + ((size_t)(y0  )*WW + (x0  ))*C + c] : 0.f;
    float sv = v00*(wx0*wy0) + v01*(wx1*wy0) + v10*(wx0*wy1) + v11*(wx1*wy1);
    accY += msk[g*P+p]*sv;
  }
  float cf = cfs[g];
  float xc = x_proj[(size_t)pix*C + c];
  y_out[(size_t)pix*C + c] = accY*(1.f-cf) + xc*cf;
}

// ---------------- K5: patch attention (3x3 softmax std) + residual ----------------
__global__ __launch_bounds__(256) void pattn_kernel(const float* __restrict__ x,
    const float* __restrict__ x1, float* __restrict__ out) {
  int pix = blockIdx.x*4 + (threadIdx.x>>6);
  int lane = threadIdx.x & 63;
  int n = pix / (HH*WW); int hw = pix % (HH*WW); int h = hw / WW; int w = hw % WW;
  size_t base = (size_t)pix*C;
  float cen[3];
  #pragma unroll
  for (int q=0;q<3;q++) cen[q] = x1[base + lane + 64*q];
  float sc[9];
  #pragma unroll
  for (int i=0;i<3;i++){
    int hy = h+i-1;
    #pragma unroll
    for (int j=0;j<3;j++){
      int wx = w+j-1;
      float a = 0.f;
      if (hy>=0 && hy<HH && wx>=0 && wx<WW){
        size_t nb = ((size_t)(n*HH+hy)*WW + wx)*C;
        #pragma unroll
        for (int q=0;q<3;q++) a += cen[q]*x1[nb + lane + 64*q];
      }
      sc[i*3+j]=a;
    }
  }
  #pragma unroll
  for (int k=0;k<9;k++){
    #pragma unroll
    for (int o=32;o>0;o>>=1) sc[k] += __shfl_xor(sc[k], o);
  }
  // softmax over 9 then unbiased std
  float m = sc[0];
  #pragma unroll
  for (int k=1;k<9;k++) m = fmaxf(m, sc[k]);
  float pr[9]; float s = 0.f;
  #pragma unroll
  for (int k=0;k<9;k++){ pr[k] = expf(sc[k]-m); s += pr[k]; }
  float inv = 1.0f/s;
  float mean = 0.f;
  #pragma unroll
  for (int k=0;k<9;k++){ pr[k] *= inv; mean += pr[k]; }
  mean *= (1.0f/9.0f);
  float var = 0.f;
  #pragma unroll
  for (int k=0;k<9;k++){ float d = pr[k]-mean; var += d*d; }
  float sd = sqrtf(var*(1.0f/8.0f));
  #pragma unroll
  for (int q=0;q<3;q++){
    int c = lane + 64*q;
    out[base+c] = x[base+c] + x1[base+c]*sd;
  }
}

extern "C" void kernel_launch(void* const* d_in, const int* in_sizes, int n_in,
                              void* d_out, int out_size, void* d_ws, size_t ws_size,
                              hipStream_t stream) {
  const float* x     = (const float*)d_in[0];
  const float* dw_w  = (const float*)d_in[1];
  const float* dw_b  = (const float*)d_in[2];
  const float* ln_g  = (const float*)d_in[3];
  const float* ln_b  = (const float*)d_in[4];
  const float* off_w = (const float*)d_in[5];
  const float* off_b = (const float*)d_in[6];
  const float* msk_w = (const float*)d_in[7];
  const float* msk_b = (const float*)d_in[8];
  const float* in_w  = (const float*)d_in[9];
  const float* in_b  = (const float*)d_in[10];
  const float* out_w = (const float*)d_in[11];
  const float* out_b = (const float*)d_in[12];
  const float* cfs_w = (const float*)d_in[13];
  const float* cfs_b = (const float*)d_in[14];
  float* outp = (float*)d_out;
  float* buf0 = (float*)d_ws;                 // x_proj
  float* buf1 = buf0 + (size_t)NPIX*C;        // u -> y2 -> x1 (in-place reuse)

  proj_kernel<<<NPIX/PPB, 192, 0, stream>>>(x, in_w, in_b, buf0);
  dw_ln_gelu_kernel<<<NPIX, 192, 0, stream>>>(x, dw_w, dw_b, ln_g, ln_b, buf1);
  dcn_kernel<<<NPIX, 192, 0, stream>>>(buf1, buf0, off_w, off_b, msk_w, msk_b,
                                       cfs_w, cfs_b, buf1);
  proj_kernel<<<NPIX/PPB, 192, 0, stream>>>(buf1, out_w, out_b, buf1);
  pattn_kernel<<<NPIX/4, 256, 0, stream>>>(x, buf1, outp);
}

// Round 2
// 385.481 us; speedup vs baseline: 1.7528x; 1.7528x over previous
//
#include <hip/hip_runtime.h>
#include <math.h>

#define NB 8
#define HH 64
#define WW 64
#define C 192
#define G 12
#define GC 16
#define P 9
#define NPIX (NB*HH*WW)

#define BM 64
#define BN 64
#define BK 16

// ---------------- tiled f32 GEMM: C[M x NSTORE] = A[M x 192] @ W[192 x NW] + bias ----------------
// writes only cols < NSTORE (NW may be padded). 256 threads, 64x64 tile, 4x4 acc/thread.
template<int NW, int NSTORE>
__global__ __launch_bounds__(256) void gemm_kernel(
    const float* __restrict__ A, const float* __restrict__ W,
    const float* __restrict__ bias, float* __restrict__ Cout) {
  __shared__ float As[BK][BM];
  __shared__ float Bs[BK][BN];
  int pix0 = blockIdx.x * BM, n0 = blockIdx.y * BN;
  int tid = threadIdx.x;
  int tx = tid & 15, ty = tid >> 4;
  float acc[4][4] = {};
  for (int k0 = 0; k0 < 192; k0 += BK) {
    { // stage A-tile (64 pixels x 16 k), transposed to As[k][m]
      int m = tid & 63, kq = tid >> 6;          // kq 0..3
      float4 v = *(const float4*)&A[(size_t)(pix0 + m)*192 + k0 + kq*4];
      As[kq*4+0][m] = v.x; As[kq*4+1][m] = v.y;
      As[kq*4+2][m] = v.z; As[kq*4+3][m] = v.w;
    }
    { // stage B-tile (16 k x 64 n)
      int nq = tid & 15, k = tid >> 4;          // k 0..15
      float4 v = *(const float4*)&W[(size_t)(k0 + k)*NW + n0 + nq*4];
      *(float4*)&Bs[k][nq*4] = v;
    }
    __syncthreads();
    #pragma unroll
    for (int k = 0; k < BK; k++) {
      float4 a4 = *(const float4*)&As[k][ty*4];
      float4 b4 = *(const float4*)&Bs[k][tx*4];
      float av[4] = {a4.x, a4.y, a4.z, a4.w};
      float bv[4] = {b4.x, b4.y, b4.z, b4.w};
      #pragma unroll
      for (int i = 0; i < 4; i++)
        #pragma unroll
        for (int j = 0; j < 4; j++)
          acc[i][j] += av[i] * bv[j];
    }
    __syncthreads();
  }
  #pragma unroll
  for (int i = 0; i < 4; i++) {
    size_t pix = pix0 + ty*4 + i;
    #pragma unroll
    for (int j = 0; j < 4; j++) {
      int n = n0 + tx*4 + j;
      if (NW == NSTORE || n < NSTORE)
        Cout[pix*NSTORE + n] = acc[i][j] + bias[n];
    }
  }
}

// ---------------- fuse off/msk/cfs weights into [192][384] (pad cols 336..383 with 0) ----------------
__global__ void fuse_w_kernel(const float* __restrict__ off_w, const float* __restrict__ off_b,
    const float* __restrict__ msk_w, const float* __restrict__ msk_b,
    const float* __restrict__ cfs_w, const float* __restrict__ cfs_b,
    float* __restrict__ wf, float* __restrict__ bf) {
  int idx = blockIdx.x*256 + threadIdx.x;
  if (idx < 192*384) {
    int k = idx / 384, n = idx % 384;
    float v = 0.f;
    if (n < 216)      v = off_w[k*216 + n];
    else if (n < 324) v = msk_w[k*108 + (n-216)];
    else if (n < 336) v = cfs_w[k*12  + (n-324)];
    wf[idx] = v;
    if (k == 0) {
      float b = 0.f;
      if (n < 216)      b = off_b[n];
      else if (n < 324) b = msk_b[n-216];
      else if (n < 336) b = cfs_b[n-324];
      bf[n] = b;
    }
  }
}

// ---------------- depthwise 5x5 + LayerNorm + exact GELU -> u ----------------
__global__ __launch_bounds__(192) void dw_ln_gelu_kernel(const float* __restrict__ x,
    const float* __restrict__ dw_w, const float* __restrict__ dw_b,
    const float* __restrict__ ln_g, const float* __restrict__ ln_b,
    float* __restrict__ u_out) {
  int pix = blockIdx.x;
  int n = pix / (HH*WW); int hw = pix % (HH*WW); int h = hw / WW; int w = hw % WW;
  int c = threadIdx.x;
  float acc = dw_b[c];
  #pragma unroll
  for (int i=0;i<5;i++){
    int hy = h + i - 2;
    if (hy < 0 || hy >= HH) continue;
    #pragma unroll
    for (int j=0;j<5;j++){
      int wx = w + j - 2;
      if (wx < 0 || wx >= WW) continue;
      acc += x[(((size_t)n*HH + hy)*WW + wx)*C + c] * dw_w[(i*5+j)*C + c];
    }
  }
  float v1 = acc, v2 = acc*acc;
  #pragma unroll
  for (int o=32;o>0;o>>=1){ v1 += __shfl_down(v1,o); v2 += __shfl_down(v2,o); }
  __shared__ float s1[3], s2[3];
  __shared__ float mu_s, rstd_s;
  int wid = threadIdx.x >> 6, lane = threadIdx.x & 63;
  if (lane==0){ s1[wid]=v1; s2[wid]=v2; }
  __syncthreads();
  if (threadIdx.x==0){
    float t1 = s1[0]+s1[1]+s1[2];
    float t2 = s2[0]+s2[1]+s2[2];
    float mu = t1/(float)C;
    float var = t2/(float)C - mu*mu;
    mu_s = mu; rstd_s = rsqrtf(var + 1e-5f);
  }
  __syncthreads();
  float uv = (acc - mu_s)*rstd_s*ln_g[c] + ln_b[c];
  uv = 0.5f*uv*(1.0f + erff(uv*0.70710678118654752f));  // exact GELU
  u_out[(size_t)pix*C + c] = uv;
}

// ---------------- DCNv3 sampling + gated blend (reads precomputed off/msk/cfs rows) ----------------
__global__ __launch_bounds__(192) void sample_kernel(const float* __restrict__ omc,
    const float* __restrict__ x_proj, float* __restrict__ y_out) {
  int pix = blockIdx.x;
  int n = pix / (HH*WW); int hw = pix % (HH*WW); int h = hw / WW; int w = hw % WW;
  int tid = threadIdx.x;
  __shared__ float offs[G*P*2];   // 216
  __shared__ float msk[G*P];      // 108
  __shared__ float cfs[G];        // 12
  const float* row = &omc[(size_t)pix*336];
  for (int o = tid; o < 336; o += 192) {
    float v = row[o];
    if (o < 216) offs[o]=v; else if (o < 324) msk[o-216]=v; else cfs[o-324]=v;
  }
  __syncthreads();
  if (tid < G) {
    float m = -1e30f;
    #pragma unroll
    for (int p=0;p<P;p++) m = fmaxf(m, msk[tid*P+p]);
    float e[P]; float s = 0.f;
    #pragma unroll
    for (int p=0;p<P;p++){ e[p] = expf(msk[tid*P+p]-m); s += e[p]; }
    float inv = 1.0f/s;
    #pragma unroll
    for (int p=0;p<P;p++) msk[tid*P+p] = e[p]*inv;
    cfs[tid] = 1.0f/(1.0f+expf(-cfs[tid]));   // sigmoid
  }
  __syncthreads();
  int c = tid, g = c >> 4;
  const float pts[3] = {-1.f, 0.f, 1.f};
  size_t baseN = (size_t)n*HH*WW*C;
  float accY = 0.f;
  #pragma unroll
  for (int p=0;p<P;p++){
    float ox = offs[2*(g*P+p)], oy = offs[2*(g*P+p)+1];
    float gx = 1.0f + (float)w + pts[p/3] + ox;   // padded-image coords (66x66)
    float gy = 1.0f + (float)h + pts[p%3] + oy;
    float x0f = floorf(gx), y0f = floorf(gy);
    float wx1 = gx - x0f, wy1 = gy - y0f;
    float wx0 = 1.f-wx1, wy0 = 1.f-wy1;
    int x0 = (int)x0f, y0 = (int)y0f;
    bool xv0 = (x0   >= 1) && (x0   <= 64);
    bool xv1 = (x0+1 >= 1) && (x0+1 <= 64);
    bool yv0 = (y0   >= 1) && (y0   <= 64);
    bool yv1 = (y0+1 >= 1) && (y0+1 <= 64);
    float v00 = (yv0 && xv0) ? x_proj[baseN + ((size_t)(y0-1)*WW + (x0-1))*C + c] : 0.f;
    float v01 = (yv0 && xv1) ? x_proj[baseN + ((size_t)(y0-1)*WW + (x0  ))*C + c] : 0.f;
    float v10 = (yv1 && xv0) ? x_proj[baseN + ((size_t)(y0  )*WW + (x0-1))*C + c] : 0.f;
    float v11 = (yv1 && xv1) ? x_proj[baseN + ((size_t)(y0  )*WW + (x0  ))*C + c] : 0.f;
    float sv = v00*(wx0*wy0) + v01*(wx1*wy0) + v10*(wx0*wy1) + v11*(wx1*wy1);
    accY += msk[g*P+p]*sv;
  }
  float cf = cfs[g];
  float xc = x_proj[(size_t)pix*C + c];
  y_out[(size_t)pix*C + c] = accY*(1.f-cf) + xc*cf;
}

// ---------------- patch attention (3x3 softmax std) + residual ----------------
__global__ __launch_bounds__(256) void pattn_kernel(const float* __restrict__ x,
    const float* __restrict__ x1, float* __restrict__ out) {
  int pix = blockIdx.x*4 + (threadIdx.x>>6);
  int lane = threadIdx.x & 63;
  int n = pix / (HH*WW); int hw = pix % (HH*WW); int h = hw / WW; int w = hw % WW;
  size_t base = (size_t)pix*C;
  float cen[3];
  #pragma unroll
  for (int q=0;q<3;q++) cen[q] = x1[base + lane + 64*q];
  float sc[9];
  #pragma unroll
  for (int i=0;i<3;i++){
    int hy = h+i-1;
    #pragma unroll
    for (int j=0;j<3;j++){
      int wx = w+j-1;
      float a = 0.f;
      if (hy>=0 && hy<HH && wx>=0 && wx<WW){
        size_t nb = ((size_t)(n*HH+hy)*WW + wx)*C;
        #pragma unroll
        for (int q=0;q<3;q++) a += cen[q]*x1[nb + lane + 64*q];
      }
      sc[i*3+j]=a;
    }
  }
  #pragma unroll
  for (int k=0;k<9;k++){
    #pragma unroll
    for (int o=32;o>0;o>>=1) sc[k] += __shfl_xor(sc[k], o);
  }
  float m = sc[0];
  #pragma unroll
  for (int k=1;k<9;k++) m = fmaxf(m, sc[k]);
  float pr[9]; float s = 0.f;
  #pragma unroll
  for (int k=0;k<9;k++){ pr[k] = expf(sc[k]-m); s += pr[k]; }
  float inv = 1.0f/s;
  float mean = 0.f;
  #pragma unroll
  for (int k=0;k<9;k++){ pr[k] *= inv; mean += pr[k]; }
  mean *= (1.0f/9.0f);
  float var = 0.f;
  #pragma unroll
  for (int k=0;k<9;k++){ float d = pr[k]-mean; var += d*d; }
  float sd = sqrtf(var*(1.0f/8.0f));
  #pragma unroll
  for (int q=0;q<3;q++){
    int c = lane + 64*q;
    out[base+c] = x[base+c] + x1[base+c]*sd;
  }
}

extern "C" void kernel_launch(void* const* d_in, const int* in_sizes, int n_in,
                              void* d_out, int out_size, void* d_ws, size_t ws_size,
                              hipStream_t stream) {
  const float* x     = (const float*)d_in[0];
  const float* dw_w  = (const float*)d_in[1];
  const float* dw_b  = (const float*)d_in[2];
  const float* ln_g  = (const float*)d_in[3];
  const float* ln_b  = (const float*)d_in[4];
  const float* off_w = (const float*)d_in[5];
  const float* off_b = (const float*)d_in[6];
  const float* msk_w = (const float*)d_in[7];
  const float* msk_b = (const float*)d_in[8];
  const float* in_w  = (const float*)d_in[9];
  const float* in_b  = (const float*)d_in[10];
  const float* out_w = (const float*)d_in[11];
  const float* out_b = (const float*)d_in[12];
  const float* cfs_w = (const float*)d_in[13];
  const float* cfs_b = (const float*)d_in[14];
  float* outp = (float*)d_out;

  float* buf0 = (float*)d_ws;                    // x_proj, later x1
  float* buf1 = buf0 + (size_t)NPIX*C;           // u, later y2
  float* buf2 = buf1 + (size_t)NPIX*C;           // offmsk rows [NPIX][336]
  float* wf   = buf2 + (size_t)NPIX*336;         // fused W [192][384]
  float* bf   = wf + 192*384;                    // fused bias [384]

  fuse_w_kernel<<<(192*384 + 255)/256, 256, 0, stream>>>(off_w, off_b, msk_w, msk_b,
                                                          cfs_w, cfs_b, wf, bf);
  // x_proj = x @ in_w + in_b
  gemm_kernel<192,192><<<dim3(NPIX/BM, 192/BN), 256, 0, stream>>>(x, in_w, in_b, buf0);
  // u = GELU(LN(dwconv(x)))
  dw_ln_gelu_kernel<<<NPIX, 192, 0, stream>>>(x, dw_w, dw_b, ln_g, ln_b, buf1);
  // offmsk = u @ wf + bf   (384 padded cols, store 336)
  gemm_kernel<384,336><<<dim3(NPIX/BM, 384/BN), 256, 0, stream>>>(buf1, wf, bf, buf2);
  // y2 = dcn-sample + gated blend   (overwrites u; sample doesn't read u)
  sample_kernel<<<NPIX, 192, 0, stream>>>(buf2, buf0, buf1);
  // x1 = y2 @ out_w + out_b   (write to buf0; x_proj dead)
  gemm_kernel<192,192><<<dim3(NPIX/BM, 192/BN), 256, 0, stream>>>(buf1, out_w, out_b, buf0);
  // out = x + x1 * patch_std
  pattn_kernel<<<NPIX/4, 256, 0, stream>>>(x, buf0, outp);
}

// Round 3
// 249.497 us; speedup vs baseline: 2.7082x; 1.5450x over previous
//
#include <hip/hip_runtime.h>
#include <hip/hip_bf16.h>
#include <math.h>

#define NB 8
#define HH 64
#define WW 64
#define C 192
#define G 12
#define GC 16
#define P 9
#define NPIX (NB*HH*WW)

typedef __attribute__((ext_vector_type(8))) short short8;
typedef __attribute__((ext_vector_type(4))) float f32x4;
typedef unsigned short ushort;

__device__ __forceinline__ ushort to_bf16(float f) {
  __hip_bfloat16 b = __float2bfloat16(f);
  return *(ushort*)&b;
}

// ---------------- convert x (f32) -> bf16, 8 elems/thread ----------------
__global__ __launch_bounds__(256) void cvt_kernel(const float* __restrict__ in,
                                                  ushort* __restrict__ out) {
  int i = blockIdx.x*256 + threadIdx.x;          // i indexes groups of 8
  float4 v0 = ((const float4*)in)[2*i];
  float4 v1 = ((const float4*)in)[2*i+1];
  short8 r;
  r[0]=to_bf16(v0.x); r[1]=to_bf16(v0.y); r[2]=to_bf16(v0.z); r[3]=to_bf16(v0.w);
  r[4]=to_bf16(v1.x); r[5]=to_bf16(v1.y); r[6]=to_bf16(v1.z); r[7]=to_bf16(v1.w);
  ((short8*)out)[i] = r;
}

// ---------------- weight prep: transpose to [n][k] bf16 + fused bias ----------------
__global__ void prep_w_kernel(const float* __restrict__ in_w, const float* __restrict__ out_w,
    const float* __restrict__ off_w, const float* __restrict__ msk_w, const float* __restrict__ cfs_w,
    const float* __restrict__ off_b, const float* __restrict__ msk_b, const float* __restrict__ cfs_b,
    ushort* __restrict__ in_wt, ushort* __restrict__ out_wt, ushort* __restrict__ wf_t,
    float* __restrict__ bf_bias) {
  int idx = blockIdx.x*256 + threadIdx.x;
  if (idx < 36864) {                       // in_wt[n][k]
    int n = idx/192, k = idx%192;
    in_wt[idx] = to_bf16(in_w[k*192 + n]);
  } else if (idx < 73728) {                // out_wt[n][k]
    int j = idx - 36864; int n = j/192, k = j%192;
    out_wt[j] = to_bf16(out_w[k*192 + n]);
  } else if (idx < 147456) {               // wf_t[n][k], n<384 (cols 336..383 zero)
    int j = idx - 73728; int n = j/192, k = j%192;
    float v = 0.f;
    if (n < 216)      v = off_w[k*216 + n];
    else if (n < 324) v = msk_w[k*108 + (n-216)];
    else if (n < 336) v = cfs_w[k*12  + (n-324)];
    wf_t[j] = to_bf16(v);
  }
  if (idx < 384) {
    float b = 0.f;
    if (idx < 216)      b = off_b[idx];
    else if (idx < 324) b = msk_b[idx-216];
    else if (idx < 336) b = cfs_b[idx-324];
    bf_bias[idx] = b;
  }
}

// ---------------- bf16 MFMA GEMM: C[M x NSTORE](f32) = A[M x 192](bf16) @ Wt^T + bias ----
// Wt is [NW][192] bf16 (row n holds column n of W, k-contiguous). 256 thr, 128x64 tile.
template<int NW, int NSTORE>
__global__ __launch_bounds__(256) void mfma_gemm(const ushort* __restrict__ A,
    const ushort* __restrict__ Wt, const float* __restrict__ bias,
    float* __restrict__ Cout) {
  __shared__ ushort As[4*128*8];   // [kb][row][8]  8KB
  __shared__ ushort Bs[4*64*8];    // [kb][n][8]    4KB
  int pix0 = blockIdx.x * 128, n0 = blockIdx.y * 64;
  int tid = threadIdx.x;
  int wid = tid >> 6, lane = tid & 63;
  int lr = lane >> 4, lc = lane & 15;

  f32x4 acc[2][4];
  #pragma unroll
  for (int m=0;m<2;m++)
    #pragma unroll
    for (int j=0;j<4;j++) acc[m][j] = (f32x4){0.f,0.f,0.f,0.f};

  // A slots: tid and tid+256 (512 total); B slot: tid (256 total)
  int sa0_kb = tid >> 7,        sa0_row = tid & 127;
  int sa1_kb = (tid+256) >> 7,  sa1_row = (tid+256) & 127;
  int sb_kb  = tid >> 6,        sb_n    = tid & 63;

  short8 pa0, pa1, pb;
  auto load_tile = [&](int k0) {
    pa0 = *(const short8*)&A[(size_t)(pix0 + sa0_row)*192 + k0 + sa0_kb*8];
    pa1 = *(const short8*)&A[(size_t)(pix0 + sa1_row)*192 + k0 + sa1_kb*8];
    pb  = *(const short8*)&Wt[(size_t)(n0 + sb_n)*192 + k0 + sb_kb*8];
  };
  load_tile(0);

  for (int t = 0; t < 6; t++) {
    __syncthreads();
    *(short8*)&As[(size_t)tid*8]        = pa0;
    *(short8*)&As[(size_t)(tid+256)*8]  = pa1;
    *(short8*)&Bs[(size_t)tid*8]        = pb;
    __syncthreads();
    if (t < 5) load_tile((t+1)*32);
    short8 a0 = *(const short8*)&As[(size_t)(lr*128 + wid*32 + lc)*8];
    short8 a1 = *(const short8*)&As[(size_t)(lr*128 + wid*32 + 16 + lc)*8];
    #pragma unroll
    for (int j=0;j<4;j++) {
      short8 b = *(const short8*)&Bs[(size_t)(lr*64 + j*16 + lc)*8];
      acc[0][j] = __builtin_amdgcn_mfma_f32_16x16x32_bf16(a0, b, acc[0][j], 0,0,0);
      acc[1][j] = __builtin_amdgcn_mfma_f32_16x16x32_bf16(a1, b, acc[1][j], 0,0,0);
    }
  }
  #pragma unroll
  for (int j=0;j<4;j++) {
    int col = n0 + j*16 + lc;
    if (NW != NSTORE && col >= NSTORE) continue;
    float bb = bias[col];
    #pragma unroll
    for (int m=0;m<2;m++) {
      size_t rbase = pix0 + wid*32 + m*16 + lr*4;
      #pragma unroll
      for (int r=0;r<4;r++)
        Cout[(rbase + r)*NSTORE + col] = acc[m][j][r] + bb;
    }
  }
}

// ---------------- depthwise 5x5 + LayerNorm + exact GELU -> u (bf16) ----------------
__global__ __launch_bounds__(192) void dw_ln_gelu_kernel(const float* __restrict__ x,
    const float* __restrict__ dw_w, const float* __restrict__ dw_b,
    const float* __restrict__ ln_g, const float* __restrict__ ln_b,
    ushort* __restrict__ u_out) {
  int pix = blockIdx.x;
  int n = pix / (HH*WW); int hw = pix % (HH*WW); int h = hw / WW; int w = hw % WW;
  int c = threadIdx.x;
  float acc = dw_b[c];
  #pragma unroll
  for (int i=0;i<5;i++){
    int hy = h + i - 2;
    if (hy < 0 || hy >= HH) continue;
    #pragma unroll
    for (int j=0;j<5;j++){
      int wx = w + j - 2;
      if (wx < 0 || wx >= WW) continue;
      acc += x[(((size_t)n*HH + hy)*WW + wx)*C + c] * dw_w[(i*5+j)*C + c];
    }
  }
  float v1 = acc, v2 = acc*acc;
  #pragma unroll
  for (int o=32;o>0;o>>=1){ v1 += __shfl_down(v1,o); v2 += __shfl_down(v2,o); }
  __shared__ float s1[3], s2[3];
  __shared__ float mu_s, rstd_s;
  int wid = threadIdx.x >> 6, lane = threadIdx.x & 63;
  if (lane==0){ s1[wid]=v1; s2[wid]=v2; }
  __syncthreads();
  if (threadIdx.x==0){
    float t1 = s1[0]+s1[1]+s1[2];
    float t2 = s2[0]+s2[1]+s2[2];
    float mu = t1/(float)C;
    float var = t2/(float)C - mu*mu;
    mu_s = mu; rstd_s = rsqrtf(var + 1e-5f);
  }
  __syncthreads();
  float uv = (acc - mu_s)*rstd_s*ln_g[c] + ln_b[c];
  uv = 0.5f*uv*(1.0f + erff(uv*0.70710678118654752f));  // exact GELU
  u_out[(size_t)pix*C + c] = to_bf16(uv);
}

// ---------------- DCNv3 sampling + gated blend -> y2 (bf16) ----------------
__global__ __launch_bounds__(192) void sample_kernel(const float* __restrict__ omc,
    const float* __restrict__ x_proj, ushort* __restrict__ y_out) {
  int pix = blockIdx.x;
  int n = pix / (HH*WW); int hw = pix % (HH*WW); int h = hw / WW; int w = hw % WW;
  int tid = threadIdx.x;
  __shared__ float row[336];
  __shared__ int   addrs[108*4];
  __shared__ float wts[108*4];
  __shared__ float msm[108];
  __shared__ float cfss[12];
  for (int o = tid; o < 336; o += 192) row[o] = omc[(size_t)pix*336 + o];
  __syncthreads();
  if (tid < 108) {
    int p = tid % 9;
    const float pts[3] = {-1.f, 0.f, 1.f};
    float gx = 1.0f + (float)w + pts[p/3] + row[2*tid];
    float gy = 1.0f + (float)h + pts[p%3] + row[2*tid+1];
    float x0f = floorf(gx), y0f = floorf(gy);
    float wx1 = gx - x0f, wy1 = gy - y0f;
    float wx0 = 1.f-wx1, wy0 = 1.f-wy1;
    int x0 = (int)x0f, y0 = (int)y0f;
    bool xv0 = (x0   >= 1) && (x0   <= 64);
    bool xv1 = (x0+1 >= 1) && (x0+1 <= 64);
    bool yv0 = (y0   >= 1) && (y0   <= 64);
    bool yv1 = (y0+1 >= 1) && (y0+1 <= 64);
    int base = n*HH*WW*C;
    int a00 = (yv0&&xv0) ? base + ((y0-1)*WW + (x0-1))*C : 0;
    int a01 = (yv0&&xv1) ? base + ((y0-1)*WW + (x0  ))*C : 0;
    int a10 = (yv1&&xv0) ? base + ((y0  )*WW + (x0-1))*C : 0;
    int a11 = (yv1&&xv1) ? base + ((y0  )*WW + (x0  ))*C : 0;
    addrs[tid*4+0]=a00; addrs[tid*4+1]=a01; addrs[tid*4+2]=a10; addrs[tid*4+3]=a11;
    wts[tid*4+0] = (yv0&&xv0) ? wx0*wy0 : 0.f;
    wts[tid*4+1] = (yv0&&xv1) ? wx1*wy0 : 0.f;
    wts[tid*4+2] = (yv1&&xv0) ? wx0*wy1 : 0.f;
    wts[tid*4+3] = (yv1&&xv1) ? wx1*wy1 : 0.f;
  } else if (tid < 120) {
    int gg = tid - 108;
    float m = -1e30f;
    #pragma unroll
    for (int p=0;p<P;p++) m = fmaxf(m, row[216+gg*P+p]);
    float e[P]; float s = 0.f;
    #pragma unroll
    for (int p=0;p<P;p++){ e[p] = expf(row[216+gg*P+p]-m); s += e[p]; }
    float inv = 1.0f/s;
    #pragma unroll
    for (int p=0;p<P;p++) msm[gg*P+p] = e[p]*inv;
  } else if (tid < 132) {
    int gg = tid - 120;
    cfss[gg] = 1.0f/(1.0f+expf(-row[324+gg]));
  }
  __syncthreads();
  int c = tid, g = c >> 4;
  float accY = 0.f;
  #pragma unroll
  for (int p=0;p<P;p++){
    int gp = g*P + p;
    int4   a4 = *(const int4*)&addrs[gp*4];
    float4 w4 = *(const float4*)&wts[gp*4];
    float  m  = msm[gp];
    float v00 = x_proj[a4.x + c];
    float v01 = x_proj[a4.y + c];
    float v10 = x_proj[a4.z + c];
    float v11 = x_proj[a4.w + c];
    accY += m*(w4.x*v00 + w4.y*v01 + w4.z*v10 + w4.w*v11);
  }
  float cf = cfss[g];
  float xc = x_proj[(size_t)pix*C + c];
  y_out[(size_t)pix*C + c] = to_bf16(accY*(1.f-cf) + xc*cf);
}

// ---------------- patch attention (3x3 softmax std) + residual ----------------
__global__ __launch_bounds__(256) void pattn_kernel(const float* __restrict__ x,
    const float* __restrict__ x1, float* __restrict__ out) {
  int pix = blockIdx.x*4 + (threadIdx.x>>6);
  int lane = threadIdx.x & 63;
  int n = pix / (HH*WW); int hw = pix % (HH*WW); int h = hw / WW; int w = hw % WW;
  size_t base = (size_t)pix*C;
  float cen[3];
  #pragma unroll
  for (int q=0;q<3;q++) cen[q] = x1[base + lane + 64*q];
  float sc[9];
  #pragma unroll
  for (int i=0;i<3;i++){
    int hy = h+i-1;
    #pragma unroll
    for (int j=0;j<3;j++){
      int wx = w+j-1;
      float a = 0.f;
      if (hy>=0 && hy<HH && wx>=0 && wx<WW){
        size_t nb = ((size_t)(n*HH+hy)*WW + wx)*C;
        #pragma unroll
        for (int q=0;q<3;q++) a += cen[q]*x1[nb + lane + 64*q];
      }
      sc[i*3+j]=a;
    }
  }
  #pragma unroll
  for (int k=0;k<9;k++){
    #pragma unroll
    for (int o=32;o>0;o>>=1) sc[k] += __shfl_xor(sc[k], o);
  }
  float m = sc[0];
  #pragma unroll
  for (int k=1;k<9;k++) m = fmaxf(m, sc[k]);
  float pr[9]; float s = 0.f;
  #pragma unroll
  for (int k=0;k<9;k++){ pr[k] = expf(sc[k]-m); s += pr[k]; }
  float inv = 1.0f/s;
  float mean = 0.f;
  #pragma unroll
  for (int k=0;k<9;k++){ pr[k] *= inv; mean += pr[k]; }
  mean *= (1.0f/9.0f);
  float var = 0.f;
  #pragma unroll
  for (int k=0;k<9;k++){ float d = pr[k]-mean; var += d*d; }
  float sd = sqrtf(var*(1.0f/8.0f));
  #pragma unroll
  for (int q=0;q<3;q++){
    int c = lane + 64*q;
    out[base+c] = x[base+c] + x1[base+c]*sd;
  }
}

extern "C" void kernel_launch(void* const* d_in, const int* in_sizes, int n_in,
                              void* d_out, int out_size, void* d_ws, size_t ws_size,
                              hipStream_t stream) {
  const float* x     = (const float*)d_in[0];
  const float* dw_w  = (const float*)d_in[1];
  const float* dw_b  = (const float*)d_in[2];
  const float* ln_g  = (const float*)d_in[3];
  const float* ln_b  = (const float*)d_in[4];
  const float* off_w = (const float*)d_in[5];
  const float* off_b = (const float*)d_in[6];
  const float* msk_w = (const float*)d_in[7];
  const float* msk_b = (const float*)d_in[8];
  const float* in_w  = (const float*)d_in[9];
  const float* in_b  = (const float*)d_in[10];
  const float* out_w = (const float*)d_in[11];
  const float* out_b = (const float*)d_in[12];
  const float* cfs_w = (const float*)d_in[13];
  const float* cfs_b = (const float*)d_in[14];
  float* outp = (float*)d_out;

  float*  xproj = (float*)d_ws;                       // NPIX*192 f32 (later x1)
  float*  omc   = xproj + (size_t)NPIX*192;           // NPIX*336 f32
  ushort* x_bf  = (ushort*)(omc + (size_t)NPIX*336);  // NPIX*192 bf16
  ushort* u_bf  = x_bf + (size_t)NPIX*192;            // NPIX*192 bf16 (u, then y2)
  ushort* in_wt = u_bf + (size_t)NPIX*192;            // 192*192
  ushort* out_wt= in_wt + 192*192;                    // 192*192
  ushort* wf_t  = out_wt + 192*192;                   // 384*192
  float*  bfb   = (float*)(wf_t + 384*192);           // 384 f32

  cvt_kernel<<<NPIX*192/8/256, 256, 0, stream>>>(x, x_bf);
  prep_w_kernel<<<(147456+255)/256, 256, 0, stream>>>(in_w, out_w, off_w, msk_w, cfs_w,
                                                       off_b, msk_b, cfs_b,
                                                       in_wt, out_wt, wf_t, bfb);
  // x_proj = x @ in_w + in_b
  mfma_gemm<192,192><<<dim3(NPIX/128, 3), 256, 0, stream>>>(x_bf, in_wt, in_b, xproj);
  // u = GELU(LN(dwconv(x)))  (bf16)
  dw_ln_gelu_kernel<<<NPIX, 192, 0, stream>>>(x, dw_w, dw_b, ln_g, ln_b, u_bf);
  // omc = u @ wf + bf
  mfma_gemm<384,336><<<dim3(NPIX/128, 6), 256, 0, stream>>>(u_bf, wf_t, bfb, omc);
  // y2 = dcn-sample + gated blend (bf16, overwrites u)
  sample_kernel<<<NPIX, 192, 0, stream>>>(omc, xproj, u_bf);
  // x1 = y2 @ out_w + out_b  (f32, overwrites x_proj)
  mfma_gemm<192,192><<<dim3(NPIX/128, 3), 256, 0, stream>>>(u_bf, out_wt, out_b, xproj);
  // out = x + x1 * patch_std
  pattn_kernel<<<NPIX/4, 256, 0, stream>>>(x, xproj, outp);
}

// Round 4
// 183.541 us; speedup vs baseline: 3.6814x; 1.3594x over previous
//
#include <hip/hip_runtime.h>
#include <hip/hip_bf16.h>
#include <math.h>

#define NB 8
#define HH 64
#define WW 64
#define C 192
#define G 12
#define GC 16
#define P 9
#define NPIX (NB*HH*WW)

typedef __attribute__((ext_vector_type(8))) short short8;
typedef __attribute__((ext_vector_type(4))) float f32x4;
typedef unsigned short ushort;

__device__ __forceinline__ ushort to_bf16(float f) {
  __hip_bfloat16 b = __float2bfloat16(f);
  return *(ushort*)&b;
}

// ---------------- convert x (f32) -> bf16, 8 elems/thread ----------------
__global__ __launch_bounds__(256) void cvt_kernel(const float* __restrict__ in,
                                                  ushort* __restrict__ out) {
  int i = blockIdx.x*256 + threadIdx.x;
  float4 v0 = ((const float4*)in)[2*i];
  float4 v1 = ((const float4*)in)[2*i+1];
  short8 r;
  r[0]=to_bf16(v0.x); r[1]=to_bf16(v0.y); r[2]=to_bf16(v0.z); r[3]=to_bf16(v0.w);
  r[4]=to_bf16(v1.x); r[5]=to_bf16(v1.y); r[6]=to_bf16(v1.z); r[7]=to_bf16(v1.w);
  ((short8*)out)[i] = r;
}

// ---------------- weight prep: transpose to [n][k] bf16 + fused bias ----------------
__global__ void prep_w_kernel(const float* __restrict__ in_w, const float* __restrict__ out_w,
    const float* __restrict__ off_w, const float* __restrict__ msk_w, const float* __restrict__ cfs_w,
    const float* __restrict__ off_b, const float* __restrict__ msk_b, const float* __restrict__ cfs_b,
    ushort* __restrict__ in_wt, ushort* __restrict__ out_wt, ushort* __restrict__ wf_t,
    float* __restrict__ bf_bias) {
  int idx = blockIdx.x*256 + threadIdx.x;
  if (idx < 36864) {
    int n = idx/192, k = idx%192;
    in_wt[idx] = to_bf16(in_w[k*192 + n]);
  } else if (idx < 73728) {
    int j = idx - 36864; int n = j/192, k = j%192;
    out_wt[j] = to_bf16(out_w[k*192 + n]);
  } else if (idx < 147456) {
    int j = idx - 73728; int n = j/192, k = j%192;
    float v = 0.f;
    if (n < 216)      v = off_w[k*216 + n];
    else if (n < 324) v = msk_w[k*108 + (n-216)];
    else if (n < 336) v = cfs_w[k*12  + (n-324)];
    wf_t[j] = to_bf16(v);
  }
  if (idx < 384) {
    float b = 0.f;
    if (idx < 216)      b = off_b[idx];
    else if (idx < 324) b = msk_b[idx-216];
    else if (idx < 336) b = cfs_b[idx-324];
    bf_bias[idx] = b;
  }
}

// ---------------- bf16 MFMA GEMM ----------------
template<int NW, int NSTORE>
__global__ __launch_bounds__(256) void mfma_gemm(const ushort* __restrict__ A,
    const ushort* __restrict__ Wt, const float* __restrict__ bias,
    float* __restrict__ Cout) {
  __shared__ ushort As[4*128*8];
  __shared__ ushort Bs[4*64*8];
  int pix0 = blockIdx.x * 128, n0 = blockIdx.y * 64;
  int tid = threadIdx.x;
  int wid = tid >> 6, lane = tid & 63;
  int lr = lane >> 4, lc = lane & 15;

  f32x4 acc[2][4];
  #pragma unroll
  for (int m=0;m<2;m++)
    #pragma unroll
    for (int j=0;j<4;j++) acc[m][j] = (f32x4){0.f,0.f,0.f,0.f};

  int sa0_kb = tid >> 7,        sa0_row = tid & 127;
  int sa1_kb = (tid+256) >> 7,  sa1_row = (tid+256) & 127;
  int sb_kb  = tid >> 6,        sb_n    = tid & 63;

  short8 pa0, pa1, pb;
  auto load_tile = [&](int k0) {
    pa0 = *(const short8*)&A[(size_t)(pix0 + sa0_row)*192 + k0 + sa0_kb*8];
    pa1 = *(const short8*)&A[(size_t)(pix0 + sa1_row)*192 + k0 + sa1_kb*8];
    pb  = *(const short8*)&Wt[(size_t)(n0 + sb_n)*192 + k0 + sb_kb*8];
  };
  load_tile(0);

  for (int t = 0; t < 6; t++) {
    __syncthreads();
    *(short8*)&As[(size_t)tid*8]        = pa0;
    *(short8*)&As[(size_t)(tid+256)*8]  = pa1;
    *(short8*)&Bs[(size_t)tid*8]        = pb;
    __syncthreads();
    if (t < 5) load_tile((t+1)*32);
    short8 a0 = *(const short8*)&As[(size_t)(lr*128 + wid*32 + lc)*8];
    short8 a1 = *(const short8*)&As[(size_t)(lr*128 + wid*32 + 16 + lc)*8];
    #pragma unroll
    for (int j=0;j<4;j++) {
      short8 b = *(const short8*)&Bs[(size_t)(lr*64 + j*16 + lc)*8];
      acc[0][j] = __builtin_amdgcn_mfma_f32_16x16x32_bf16(a0, b, acc[0][j], 0,0,0);
      acc[1][j] = __builtin_amdgcn_mfma_f32_16x16x32_bf16(a1, b, acc[1][j], 0,0,0);
    }
  }
  #pragma unroll
  for (int j=0;j<4;j++) {
    int col = n0 + j*16 + lc;
    if (NW != NSTORE && col >= NSTORE) continue;
    float bb = bias[col];
    #pragma unroll
    for (int m=0;m<2;m++) {
      size_t rbase = pix0 + wid*32 + m*16 + lr*4;
      #pragma unroll
      for (int r=0;r<4;r++)
        Cout[(rbase + r)*NSTORE + col] = acc[m][j][r] + bb;
    }
  }
}

// ------- depthwise 5x5 + LN + GELU, sliding-window: block = 16-pixel row segment -------
// grid: NB*HH*4 blocks, 192 threads (thread = channel). Each input load feeds up to
// 5 accumulators; LN via LDS transpose reduction.
#define SEG 16
__global__ __launch_bounds__(192) void dw_ln_gelu_kernel(const float* __restrict__ x,
    const float* __restrict__ dw_w, const float* __restrict__ dw_b,
    const float* __restrict__ ln_g, const float* __restrict__ ln_b,
    ushort* __restrict__ u_out) {
  int blk = blockIdx.x;                // ((n*HH + h)*4 + qw)
  int qw = blk & 3; int nh = blk >> 2;
  int h = nh & 63, n = nh >> 6;
  int c = threadIdx.x;
  int w0 = qw * SEG;

  float kw[25];
  #pragma unroll
  for (int t=0;t<25;t++) kw[t] = dw_w[t*C + c];

  float acc[SEG];
  float bb = dw_b[c];
  #pragma unroll
  for (int i=0;i<SEG;i++) acc[i] = bb;

  #pragma unroll
  for (int i=0;i<5;i++) {
    int hy = h + i - 2;
    if (hy < 0 || hy >= HH) continue;          // uniform branch
    const float* rowp = &x[(((size_t)n*HH + hy)*WW)*C + c];
    #pragma unroll
    for (int wi=0; wi<SEG+4; wi++) {
      int w_in = w0 - 2 + wi;
      if (w_in < 0 || w_in >= WW) continue;    // uniform branch
      float v = rowp[(size_t)w_in*C];
      #pragma unroll
      for (int j=0;j<5;j++) {
        int a = wi - j;                        // output index in segment
        if (a >= 0 && a < SEG) acc[a] += v * kw[i*5+j];
      }
    }
  }

  // LN reduction via LDS transpose
  __shared__ float lds_acc[SEG][C+1];
  __shared__ float part1[SEG][12], part2[SEG][12];
  __shared__ float mu_s[SEG], rs_s[SEG];
  #pragma unroll
  for (int i=0;i<SEG;i++) lds_acc[i][c] = acc[i];
  __syncthreads();
  {
    int p = threadIdx.x & 15, chunk = threadIdx.x >> 4;   // 16 x 12
    float s1 = 0.f, s2 = 0.f;
    #pragma unroll
    for (int k=0;k<16;k++) {
      float v = lds_acc[p][chunk*16 + k];
      s1 += v; s2 += v*v;
    }
    part1[p][chunk] = s1; part2[p][chunk] = s2;
  }
  __syncthreads();
  if (threadIdx.x < SEG) {
    int p = threadIdx.x;
    float t1 = 0.f, t2 = 0.f;
    #pragma unroll
    for (int k=0;k<12;k++){ t1 += part1[p][k]; t2 += part2[p][k]; }
    float mu = t1 * (1.0f/C);
    float var = t2 * (1.0f/C) - mu*mu;
    mu_s[p] = mu; rs_s[p] = rsqrtf(var + 1e-5f);
  }
  __syncthreads();
  float gg = ln_g[c], lb = ln_b[c];
  size_t obase = ((size_t)nh*WW + w0)*C + c;
  #pragma unroll
  for (int i=0;i<SEG;i++) {
    float uv = (acc[i] - mu_s[i])*rs_s[i]*gg + lb;
    uv = 0.5f*uv*(1.0f + erff(uv*0.70710678118654752f));
    u_out[obase + (size_t)i*C] = to_bf16(uv);
  }
}

// ---------------- DCNv3 sampling + gated blend -> y2 (bf16) ----------------
__global__ __launch_bounds__(192) void sample_kernel(const float* __restrict__ omc,
    const float* __restrict__ x_proj, ushort* __restrict__ y_out) {
  int pix = blockIdx.x;
  int n = pix / (HH*WW); int hw = pix % (HH*WW); int h = hw / WW; int w = hw % WW;
  int tid = threadIdx.x;
  __shared__ float row[336];
  __shared__ int   addrs[108*4];
  __shared__ float wts[108*4];
  __shared__ float msm[108];
  __shared__ float cfss[12];
  for (int o = tid; o < 336; o += 192) row[o] = omc[(size_t)pix*336 + o];
  __syncthreads();
  if (tid < 108) {
    int p = tid % 9;
    const float pts[3] = {-1.f, 0.f, 1.f};
    float gx = 1.0f + (float)w + pts[p/3] + row[2*tid];
    float gy = 1.0f + (float)h + pts[p%3] + row[2*tid+1];
    float x0f = floorf(gx), y0f = floorf(gy);
    float wx1 = gx - x0f, wy1 = gy - y0f;
    float wx0 = 1.f-wx1, wy0 = 1.f-wy1;
    int x0 = (int)x0f, y0 = (int)y0f;
    bool xv0 = (x0   >= 1) && (x0   <= 64);
    bool xv1 = (x0+1 >= 1) && (x0+1 <= 64);
    bool yv0 = (y0   >= 1) && (y0   <= 64);
    bool yv1 = (y0+1 >= 1) && (y0+1 <= 64);
    int base = n*HH*WW*C;
    int a00 = (yv0&&xv0) ? base + ((y0-1)*WW + (x0-1))*C : 0;
    int a01 = (yv0&&xv1) ? base + ((y0-1)*WW + (x0  ))*C : 0;
    int a10 = (yv1&&xv0) ? base + ((y0  )*WW + (x0-1))*C : 0;
    int a11 = (yv1&&xv1) ? base + ((y0  )*WW + (x0  ))*C : 0;
    addrs[tid*4+0]=a00; addrs[tid*4+1]=a01; addrs[tid*4+2]=a10; addrs[tid*4+3]=a11;
    wts[tid*4+0] = (yv0&&xv0) ? wx0*wy0 : 0.f;
    wts[tid*4+1] = (yv0&&xv1) ? wx1*wy0 : 0.f;
    wts[tid*4+2] = (yv1&&xv0) ? wx0*wy1 : 0.f;
    wts[tid*4+3] = (yv1&&xv1) ? wx1*wy1 : 0.f;
  } else if (tid < 120) {
    int gg = tid - 108;
    float m = -1e30f;
    #pragma unroll
    for (int p=0;p<P;p++) m = fmaxf(m, row[216+gg*P+p]);
    float e[P]; float s = 0.f;
    #pragma unroll
    for (int p=0;p<P;p++){ e[p] = expf(row[216+gg*P+p]-m); s += e[p]; }
    float inv = 1.0f/s;
    #pragma unroll
    for (int p=0;p<P;p++) msm[gg*P+p] = e[p]*inv;
  } else if (tid < 132) {
    int gg = tid - 120;
    cfss[gg] = 1.0f/(1.0f+expf(-row[324+gg]));
  }
  __syncthreads();
  int c = tid, g = c >> 4;
  float accY = 0.f;
  #pragma unroll
  for (int p=0;p<P;p++){
    int gp = g*P + p;
    int4   a4 = *(const int4*)&addrs[gp*4];
    float4 w4 = *(const float4*)&wts[gp*4];
    float  m  = msm[gp];
    float v00 = x_proj[a4.x + c];
    float v01 = x_proj[a4.y + c];
    float v10 = x_proj[a4.z + c];
    float v11 = x_proj[a4.w + c];
    accY += m*(w4.x*v00 + w4.y*v01 + w4.z*v10 + w4.w*v11);
  }
  float cf = cfss[g];
  float xc = x_proj[(size_t)pix*C + c];
  y_out[(size_t)pix*C + c] = to_bf16(accY*(1.f-cf) + xc*cf);
}

// ---------------- patch attention (3x3 softmax std) + residual ----------------
__global__ __launch_bounds__(256) void pattn_kernel(const float* __restrict__ x,
    const float* __restrict__ x1, float* __restrict__ out) {
  int pix = blockIdx.x*4 + (threadIdx.x>>6);
  int lane = threadIdx.x & 63;
  int n = pix / (HH*WW); int hw = pix % (HH*WW); int h = hw / WW; int w = hw % WW;
  size_t base = (size_t)pix*C;
  float cen[3];
  #pragma unroll
  for (int q=0;q<3;q++) cen[q] = x1[base + lane + 64*q];
  float sc[9];
  #pragma unroll
  for (int i=0;i<3;i++){
    int hy = h+i-1;
    #pragma unroll
    for (int j=0;j<3;j++){
      int wx = w+j-1;
      float a = 0.f;
      if (hy>=0 && hy<HH && wx>=0 && wx<WW){
        size_t nb = ((size_t)(n*HH+hy)*WW + wx)*C;
        #pragma unroll
        for (int q=0;q<3;q++) a += cen[q]*x1[nb + lane + 64*q];
      }
      sc[i*3+j]=a;
    }
  }
  #pragma unroll
  for (int k=0;k<9;k++){
    #pragma unroll
    for (int o=32;o>0;o>>=1) sc[k] += __shfl_xor(sc[k], o);
  }
  float m = sc[0];
  #pragma unroll
  for (int k=1;k<9;k++) m = fmaxf(m, sc[k]);
  float pr[9]; float s = 0.f;
  #pragma unroll
  for (int k=0;k<9;k++){ pr[k] = expf(sc[k]-m); s += pr[k]; }
  float inv = 1.0f/s;
  float mean = 0.f;
  #pragma unroll
  for (int k=0;k<9;k++){ pr[k] *= inv; mean += pr[k]; }
  mean *= (1.0f/9.0f);
  float var = 0.f;
  #pragma unroll
  for (int k=0;k<9;k++){ float d = pr[k]-mean; var += d*d; }
  float sd = sqrtf(var*(1.0f/8.0f));
  #pragma unroll
  for (int q=0;q<3;q++){
    int c = lane + 64*q;
    out[base+c] = x[base+c] + x1[base+c]*sd;
  }
}

extern "C" void kernel_launch(void* const* d_in, const int* in_sizes, int n_in,
                              void* d_out, int out_size, void* d_ws, size_t ws_size,
                              hipStream_t stream) {
  const float* x     = (const float*)d_in[0];
  const float* dw_w  = (const float*)d_in[1];
  const float* dw_b  = (const float*)d_in[2];
  const float* ln_g  = (const float*)d_in[3];
  const float* ln_b  = (const float*)d_in[4];
  const float* off_w = (const float*)d_in[5];
  const float* off_b = (const float*)d_in[6];
  const float* msk_w = (const float*)d_in[7];
  const float* msk_b = (const float*)d_in[8];
  const float* in_w  = (const float*)d_in[9];
  const float* in_b  = (const float*)d_in[10];
  const float* out_w = (const float*)d_in[11];
  const float* out_b = (const float*)d_in[12];
  const float* cfs_w = (const float*)d_in[13];
  const float* cfs_b = (const float*)d_in[14];
  float* outp = (float*)d_out;

  float*  xproj = (float*)d_ws;
  float*  omc   = xproj + (size_t)NPIX*192;
  ushort* x_bf  = (ushort*)(omc + (size_t)NPIX*336);
  ushort* u_bf  = x_bf + (size_t)NPIX*192;
  ushort* in_wt = u_bf + (size_t)NPIX*192;
  ushort* out_wt= in_wt + 192*192;
  ushort* wf_t  = out_wt + 192*192;
  float*  bfb   = (float*)(wf_t + 384*192);

  cvt_kernel<<<NPIX*192/8/256, 256, 0, stream>>>(x, x_bf);
  prep_w_kernel<<<(147456+255)/256, 256, 0, stream>>>(in_w, out_w, off_w, msk_w, cfs_w,
                                                       off_b, msk_b, cfs_b,
                                                       in_wt, out_wt, wf_t, bfb);
  mfma_gemm<192,192><<<dim3(NPIX/128, 3), 256, 0, stream>>>(x_bf, in_wt, in_b, xproj);
  dw_ln_gelu_kernel<<<NB*HH*4, 192, 0, stream>>>(x, dw_w, dw_b, ln_g, ln_b, u_bf);
  mfma_gemm<384,336><<<dim3(NPIX/128, 6), 256, 0, stream>>>(u_bf, wf_t, bfb, omc);
  sample_kernel<<<NPIX, 192, 0, stream>>>(omc, xproj, u_bf);
  mfma_gemm<192,192><<<dim3(NPIX/128, 3), 256, 0, stream>>>(u_bf, out_wt, out_b, xproj);
  pattn_kernel<<<NPIX/4, 256, 0, stream>>>(x, xproj, outp);
}

// Round 5
// 158.967 us; speedup vs baseline: 4.2505x; 1.1546x over previous
//
#include <hip/hip_runtime.h>
#include <hip/hip_bf16.h>
#include <math.h>

#define NB 8
#define HH 64
#define WW 64
#define C 192
#define G 12
#define GC 16
#define P 9
#define NPIX (NB*HH*WW)

typedef __attribute__((ext_vector_type(8))) short short8;
typedef __attribute__((ext_vector_type(4))) float f32x4;
typedef unsigned short ushort;

__device__ __forceinline__ ushort to_bf16(float f) {
  __hip_bfloat16 b = __float2bfloat16(f);
  return *(ushort*)&b;
}

// ---------------- convert x (f32) -> bf16, 8 elems/thread ----------------
__global__ __launch_bounds__(256) void cvt_kernel(const float* __restrict__ in,
                                                  ushort* __restrict__ out) {
  int i = blockIdx.x*256 + threadIdx.x;
  float4 v0 = ((const float4*)in)[2*i];
  float4 v1 = ((const float4*)in)[2*i+1];
  short8 r;
  r[0]=to_bf16(v0.x); r[1]=to_bf16(v0.y); r[2]=to_bf16(v0.z); r[3]=to_bf16(v0.w);
  r[4]=to_bf16(v1.x); r[5]=to_bf16(v1.y); r[6]=to_bf16(v1.z); r[7]=to_bf16(v1.w);
  ((short8*)out)[i] = r;
}

// ---------------- weight prep: transpose to [n][k] bf16 + fused bias ----------------
__global__ void prep_w_kernel(const float* __restrict__ in_w, const float* __restrict__ out_w,
    const float* __restrict__ off_w, const float* __restrict__ msk_w, const float* __restrict__ cfs_w,
    const float* __restrict__ off_b, const float* __restrict__ msk_b, const float* __restrict__ cfs_b,
    ushort* __restrict__ in_wt, ushort* __restrict__ out_wt, ushort* __restrict__ wf_t,
    float* __restrict__ bf_bias) {
  int idx = blockIdx.x*256 + threadIdx.x;
  if (idx < 36864) {
    int n = idx/192, k = idx%192;
    in_wt[idx] = to_bf16(in_w[k*192 + n]);
  } else if (idx < 73728) {
    int j = idx - 36864; int n = j/192, k = j%192;
    out_wt[j] = to_bf16(out_w[k*192 + n]);
  } else if (idx < 147456) {
    int j = idx - 73728; int n = j/192, k = j%192;
    float v = 0.f;
    if (n < 216)      v = off_w[k*216 + n];
    else if (n < 324) v = msk_w[k*108 + (n-216)];
    else if (n < 336) v = cfs_w[k*12  + (n-324)];
    wf_t[j] = to_bf16(v);
  }
  if (idx < 384) {
    float b = 0.f;
    if (idx < 216)      b = off_b[idx];
    else if (idx < 324) b = msk_b[idx-216];
    else if (idx < 336) b = cfs_b[idx-324];
    bf_bias[idx] = b;
  }
}

// ---------------- bf16 MFMA GEMM ----------------
template<int NW, int NSTORE>
__global__ __launch_bounds__(256) void mfma_gemm(const ushort* __restrict__ A,
    const ushort* __restrict__ Wt, const float* __restrict__ bias,
    float* __restrict__ Cout) {
  __shared__ ushort As[4*128*8];
  __shared__ ushort Bs[4*64*8];
  int pix0 = blockIdx.x * 128, n0 = blockIdx.y * 64;
  int tid = threadIdx.x;
  int wid = tid >> 6, lane = tid & 63;
  int lr = lane >> 4, lc = lane & 15;

  f32x4 acc[2][4];
  #pragma unroll
  for (int m=0;m<2;m++)
    #pragma unroll
    for (int j=0;j<4;j++) acc[m][j] = (f32x4){0.f,0.f,0.f,0.f};

  int sa0_kb = tid >> 7,        sa0_row = tid & 127;
  int sa1_kb = (tid+256) >> 7,  sa1_row = (tid+256) & 127;
  int sb_kb  = tid >> 6,        sb_n    = tid & 63;

  short8 pa0, pa1, pb;
  auto load_tile = [&](int k0) {
    pa0 = *(const short8*)&A[(size_t)(pix0 + sa0_row)*192 + k0 + sa0_kb*8];
    pa1 = *(const short8*)&A[(size_t)(pix0 + sa1_row)*192 + k0 + sa1_kb*8];
    pb  = *(const short8*)&Wt[(size_t)(n0 + sb_n)*192 + k0 + sb_kb*8];
  };
  load_tile(0);

  for (int t = 0; t < 6; t++) {
    __syncthreads();
    *(short8*)&As[(size_t)tid*8]        = pa0;
    *(short8*)&As[(size_t)(tid+256)*8]  = pa1;
    *(short8*)&Bs[(size_t)tid*8]        = pb;
    __syncthreads();
    if (t < 5) load_tile((t+1)*32);
    short8 a0 = *(const short8*)&As[(size_t)(lr*128 + wid*32 + lc)*8];
    short8 a1 = *(const short8*)&As[(size_t)(lr*128 + wid*32 + 16 + lc)*8];
    #pragma unroll
    for (int j=0;j<4;j++) {
      short8 b = *(const short8*)&Bs[(size_t)(lr*64 + j*16 + lc)*8];
      acc[0][j] = __builtin_amdgcn_mfma_f32_16x16x32_bf16(a0, b, acc[0][j], 0,0,0);
      acc[1][j] = __builtin_amdgcn_mfma_f32_16x16x32_bf16(a1, b, acc[1][j], 0,0,0);
    }
  }
  #pragma unroll
  for (int j=0;j<4;j++) {
    int col = n0 + j*16 + lc;
    if (NW != NSTORE && col >= NSTORE) continue;
    float bb = bias[col];
    #pragma unroll
    for (int m=0;m<2;m++) {
      size_t rbase = pix0 + wid*32 + m*16 + lr*4;
      #pragma unroll
      for (int r=0;r<4;r++)
        Cout[(rbase + r)*NSTORE + col] = acc[m][j][r] + bb;
    }
  }
}

// ------- depthwise 5x5 + LN + GELU, sliding-window: block = 16-pixel row segment -------
#define SEG 16
__global__ __launch_bounds__(192) void dw_ln_gelu_kernel(const float* __restrict__ x,
    const float* __restrict__ dw_w, const float* __restrict__ dw_b,
    const float* __restrict__ ln_g, const float* __restrict__ ln_b,
    ushort* __restrict__ u_out) {
  int blk = blockIdx.x;                // ((n*HH + h)*4 + qw)
  int qw = blk & 3; int nh = blk >> 2;
  int h = nh & 63, n = nh >> 6;
  int c = threadIdx.x;
  int w0 = qw * SEG;

  float kw[25];
  #pragma unroll
  for (int t=0;t<25;t++) kw[t] = dw_w[t*C + c];

  float acc[SEG];
  float bb = dw_b[c];
  #pragma unroll
  for (int i=0;i<SEG;i++) acc[i] = bb;

  #pragma unroll
  for (int i=0;i<5;i++) {
    int hy = h + i - 2;
    if (hy < 0 || hy >= HH) continue;
    const float* rowp = &x[(((size_t)n*HH + hy)*WW)*C + c];
    #pragma unroll
    for (int wi=0; wi<SEG+4; wi++) {
      int w_in = w0 - 2 + wi;
      if (w_in < 0 || w_in >= WW) continue;
      float v = rowp[(size_t)w_in*C];
      #pragma unroll
      for (int j=0;j<5;j++) {
        int a = wi - j;
        if (a >= 0 && a < SEG) acc[a] += v * kw[i*5+j];
      }
    }
  }

  __shared__ float lds_acc[SEG][C+1];
  __shared__ float part1[SEG][12], part2[SEG][12];
  __shared__ float mu_s[SEG], rs_s[SEG];
  #pragma unroll
  for (int i=0;i<SEG;i++) lds_acc[i][c] = acc[i];
  __syncthreads();
  {
    int p = threadIdx.x & 15, chunk = threadIdx.x >> 4;
    float s1 = 0.f, s2 = 0.f;
    #pragma unroll
    for (int k=0;k<16;k++) {
      float v = lds_acc[p][chunk*16 + k];
      s1 += v; s2 += v*v;
    }
    part1[p][chunk] = s1; part2[p][chunk] = s2;
  }
  __syncthreads();
  if (threadIdx.x < SEG) {
    int p = threadIdx.x;
    float t1 = 0.f, t2 = 0.f;
    #pragma unroll
    for (int k=0;k<12;k++){ t1 += part1[p][k]; t2 += part2[p][k]; }
    float mu = t1 * (1.0f/C);
    float var = t2 * (1.0f/C) - mu*mu;
    mu_s[p] = mu; rs_s[p] = rsqrtf(var + 1e-5f);
  }
  __syncthreads();
  float gg = ln_g[c], lb = ln_b[c];
  size_t obase = ((size_t)nh*WW + w0)*C + c;
  #pragma unroll
  for (int i=0;i<SEG;i++) {
    float uv = (acc[i] - mu_s[i])*rs_s[i]*gg + lb;
    uv = 0.5f*uv*(1.0f + erff(uv*0.70710678118654752f));
    u_out[obase + (size_t)i*C] = to_bf16(uv);
  }
}

// ---------------- DCNv3 sampling + gated blend, 4 px/block -> y2 (bf16) ----------------
// addrs = validity-masked BYTE offsets into x_proj; wts premultiplied by softmax mask.
#define SPX 4
__global__ __launch_bounds__(192) void sample_kernel(const float* __restrict__ omc,
    const float* __restrict__ x_proj, ushort* __restrict__ y_out) {
  int pix0 = blockIdx.x * SPX;
  int n = pix0 >> 12;                  // 4096 px per image
  int hw = pix0 & 4095; int h = hw >> 6; int w0 = hw & 63;
  int tid = threadIdx.x;
  __shared__ int   addrs[SPX][108][4];
  __shared__ float wts[SPX][108][4];
  __shared__ float msm[SPX][108];
  __shared__ float cfss[SPX][12];

  // B1: per-(px,g,p) taps + raw bilinear wts; softmax; sigmoid (disjoint thread ranges)
  for (int i = tid; i < SPX*108; i += 192) {
    int px = i / 108, gp = i % 108;
    int p = gp % 9;
    const float pts[3] = {-1.f, 0.f, 1.f};
    float ox = omc[(size_t)(pix0+px)*336 + 2*gp];
    float oy = omc[(size_t)(pix0+px)*336 + 2*gp + 1];
    float gx = 1.0f + (float)(w0+px) + pts[p/3] + ox;
    float gy = 1.0f + (float)h + pts[p%3] + oy;
    float x0f = floorf(gx), y0f = floorf(gy);
    float wx1 = gx - x0f, wy1 = gy - y0f;
    float wx0 = 1.f-wx1, wy0 = 1.f-wy1;
    int x0 = (int)x0f, y0 = (int)y0f;
    bool xv0 = (x0   >= 1) && (x0   <= 64);
    bool xv1 = (x0+1 >= 1) && (x0+1 <= 64);
    bool yv0 = (y0   >= 1) && (y0   <= 64);
    bool yv1 = (y0+1 >= 1) && (y0+1 <= 64);
    int base = n*HH*WW*C;               // element index; *4 -> bytes (max ~25MB, fits i32)
    addrs[px][gp][0] = (yv0&&xv0) ? (base + ((y0-1)*WW + (x0-1))*C)*4 : 0;
    addrs[px][gp][1] = (yv0&&xv1) ? (base + ((y0-1)*WW + (x0  ))*C)*4 : 0;
    addrs[px][gp][2] = (yv1&&xv0) ? (base + ((y0  )*WW + (x0-1))*C)*4 : 0;
    addrs[px][gp][3] = (yv1&&xv1) ? (base + ((y0  )*WW + (x0  ))*C)*4 : 0;
    wts[px][gp][0] = (yv0&&xv0) ? wx0*wy0 : 0.f;
    wts[px][gp][1] = (yv0&&xv1) ? wx1*wy0 : 0.f;
    wts[px][gp][2] = (yv1&&xv0) ? wx0*wy1 : 0.f;
    wts[px][gp][3] = (yv1&&xv1) ? wx1*wy1 : 0.f;
  }
  if (tid < SPX*12) {                    // softmax -> msm
    int px = tid / 12, gg = tid % 12;
    const float* mrow = &omc[(size_t)(pix0+px)*336 + 216 + gg*9];
    float m = -1e30f;
    #pragma unroll
    for (int p=0;p<P;p++) m = fmaxf(m, mrow[p]);
    float e[P]; float s = 0.f;
    #pragma unroll
    for (int p=0;p<P;p++){ e[p] = expf(mrow[p]-m); s += e[p]; }
    float inv = 1.0f/s;
    #pragma unroll
    for (int p=0;p<P;p++) msm[px][gg*9+p] = e[p]*inv;
  } else if (tid < SPX*12*2) {           // sigmoid -> cfs
    int q = tid - SPX*12;
    int px = q / 12, gg = q % 12;
    cfss[px][gg] = 1.0f/(1.0f+expf(-omc[(size_t)(pix0+px)*336 + 324 + gg]));
  }
  __syncthreads();
  // B2: premultiply softmax mask into wts
  for (int i = tid; i < SPX*108; i += 192) {
    int px = i / 108, gp = i % 108;
    float m = msm[px][gp];
    f32x4 w4 = *(f32x4*)&wts[px][gp][0];
    w4 *= m;
    *(f32x4*)&wts[px][gp][0] = w4;
  }
  __syncthreads();
  // C: gather + blend
  int c = tid, g = c >> 4;
  int c4 = c * 4;
  const char* xb = (const char*)x_proj;
  #pragma unroll
  for (int px = 0; px < SPX; px++) {
    float accY = 0.f;
    #pragma unroll
    for (int p=0;p<P;p++){
      int gp = g*P + p;
      int4   a4 = *(const int4*)&addrs[px][gp][0];
      float4 w4 = *(const float4*)&wts[px][gp][0];
      float v00 = *(const float*)(xb + (unsigned)(a4.x + c4));
      float v01 = *(const float*)(xb + (unsigned)(a4.y + c4));
      float v10 = *(const float*)(xb + (unsigned)(a4.z + c4));
      float v11 = *(const float*)(xb + (unsigned)(a4.w + c4));
      accY += w4.x*v00 + w4.y*v01 + w4.z*v10 + w4.w*v11;
    }
    float cf = cfss[px][g];
    float xc = x_proj[(size_t)(pix0+px)*C + c];
    y_out[(size_t)(pix0+px)*C + c] = to_bf16(accY*(1.f-cf) + xc*cf);
  }
}

// ---------------- patch attention (3x3 softmax std) + residual ----------------
__global__ __launch_bounds__(256) void pattn_kernel(const float* __restrict__ x,
    const float* __restrict__ x1, float* __restrict__ out) {
  int pix = blockIdx.x*4 + (threadIdx.x>>6);
  int lane = threadIdx.x & 63;
  int n = pix / (HH*WW); int hw = pix % (HH*WW); int h = hw / WW; int w = hw % WW;
  size_t base = (size_t)pix*C;
  float cen[3];
  #pragma unroll
  for (int q=0;q<3;q++) cen[q] = x1[base + lane + 64*q];
  float sc[9];
  #pragma unroll
  for (int i=0;i<3;i++){
    int hy = h+i-1;
    #pragma unroll
    for (int j=0;j<3;j++){
      int wx = w+j-1;
      float a = 0.f;
      if (hy>=0 && hy<HH && wx>=0 && wx<WW){
        size_t nb = ((size_t)(n*HH+hy)*WW + wx)*C;
        #pragma unroll
        for (int q=0;q<3;q++) a += cen[q]*x1[nb + lane + 64*q];
      }
      sc[i*3+j]=a;
    }
  }
  #pragma unroll
  for (int k=0;k<9;k++){
    #pragma unroll
    for (int o=32;o>0;o>>=1) sc[k] += __shfl_xor(sc[k], o);
  }
  float m = sc[0];
  #pragma unroll
  for (int k=1;k<9;k++) m = fmaxf(m, sc[k]);
  float pr[9]; float s = 0.f;
  #pragma unroll
  for (int k=0;k<9;k++){ pr[k] = expf(sc[k]-m); s += pr[k]; }
  float inv = 1.0f/s;
  float mean = 0.f;
  #pragma unroll
  for (int k=0;k<9;k++){ pr[k] *= inv; mean += pr[k]; }
  mean *= (1.0f/9.0f);
  float var = 0.f;
  #pragma unroll
  for (int k=0;k<9;k++){ float d = pr[k]-mean; var += d*d; }
  float sd = sqrtf(var*(1.0f/8.0f));
  #pragma unroll
  for (int q=0;q<3;q++){
    int c = lane + 64*q;
    out[base+c] = x[base+c] + x1[base+c]*sd;
  }
}

extern "C" void kernel_launch(void* const* d_in, const int* in_sizes, int n_in,
                              void* d_out, int out_size, void* d_ws, size_t ws_size,
                              hipStream_t stream) {
  const float* x     = (const float*)d_in[0];
  const float* dw_w  = (const float*)d_in[1];
  const float* dw_b  = (const float*)d_in[2];
  const float* ln_g  = (const float*)d_in[3];
  const float* ln_b  = (const float*)d_in[4];
  const float* off_w = (const float*)d_in[5];
  const float* off_b = (const float*)d_in[6];
  const float* msk_w = (const float*)d_in[7];
  const float* msk_b = (const float*)d_in[8];
  const float* in_w  = (const float*)d_in[9];
  const float* in_b  = (const float*)d_in[10];
  const float* out_w = (const float*)d_in[11];
  const float* out_b = (const float*)d_in[12];
  const float* cfs_w = (const float*)d_in[13];
  const float* cfs_b = (const float*)d_in[14];
  float* outp = (float*)d_out;

  float*  xproj = (float*)d_ws;
  float*  omc   = xproj + (size_t)NPIX*192;
  ushort* x_bf  = (ushort*)(omc + (size_t)NPIX*336);
  ushort* u_bf  = x_bf + (size_t)NPIX*192;
  ushort* in_wt = u_bf + (size_t)NPIX*192;
  ushort* out_wt= in_wt + 192*192;
  ushort* wf_t  = out_wt + 192*192;
  float*  bfb   = (float*)(wf_t + 384*192);

  cvt_kernel<<<NPIX*192/8/256, 256, 0, stream>>>(x, x_bf);
  prep_w_kernel<<<(147456+255)/256, 256, 0, stream>>>(in_w, out_w, off_w, msk_w, cfs_w,
                                                       off_b, msk_b, cfs_b,
                                                       in_wt, out_wt, wf_t, bfb);
  mfma_gemm<192,192><<<dim3(NPIX/128, 3), 256, 0, stream>>>(x_bf, in_wt, in_b, xproj);
  dw_ln_gelu_kernel<<<NB*HH*4, 192, 0, stream>>>(x, dw_w, dw_b, ln_g, ln_b, u_bf);
  mfma_gemm<384,336><<<dim3(NPIX/128, 6), 256, 0, stream>>>(u_bf, wf_t, bfb, omc);
  sample_kernel<<<NPIX/SPX, 192, 0, stream>>>(omc, xproj, u_bf);
  mfma_gemm<192,192><<<dim3(NPIX/128, 3), 256, 0, stream>>>(u_bf, out_wt, out_b, xproj);
  pattn_kernel<<<NPIX/4, 256, 0, stream>>>(x, xproj, outp);
}

// Round 6
// 156.723 us; speedup vs baseline: 4.3114x; 1.0143x over previous
//
#include <hip/hip_runtime.h>
#include <hip/hip_bf16.h>
#include <math.h>

#define NB 8
#define HH 64
#define WW 64
#define C 192
#define G 12
#define GC 16
#define P 9
#define NPIX (NB*HH*WW)

typedef __attribute__((ext_vector_type(8))) short short8;
typedef __attribute__((ext_vector_type(4))) float f32x4;
typedef unsigned short ushort;

__device__ __forceinline__ ushort to_bf16(float f) {
  __hip_bfloat16 b = __float2bfloat16(f);
  return *(ushort*)&b;
}
__device__ __forceinline__ float bf2f(ushort u) {
  union { unsigned u; float f; } cv; cv.u = ((unsigned)u) << 16; return cv.f;
}

// ---------------- convert x (f32) -> bf16, 8 elems/thread ----------------
__global__ __launch_bounds__(256) void cvt_kernel(const float* __restrict__ in,
                                                  ushort* __restrict__ out) {
  int i = blockIdx.x*256 + threadIdx.x;
  float4 v0 = ((const float4*)in)[2*i];
  float4 v1 = ((const float4*)in)[2*i+1];
  short8 r;
  r[0]=to_bf16(v0.x); r[1]=to_bf16(v0.y); r[2]=to_bf16(v0.z); r[3]=to_bf16(v0.w);
  r[4]=to_bf16(v1.x); r[5]=to_bf16(v1.y); r[6]=to_bf16(v1.z); r[7]=to_bf16(v1.w);
  ((short8*)out)[i] = r;
}

// ---------------- weight prep: transpose to [n][k] bf16 + fused bias ----------------
__global__ void prep_w_kernel(const float* __restrict__ in_w, const float* __restrict__ out_w,
    const float* __restrict__ off_w, const float* __restrict__ msk_w, const float* __restrict__ cfs_w,
    const float* __restrict__ off_b, const float* __restrict__ msk_b, const float* __restrict__ cfs_b,
    ushort* __restrict__ in_wt, ushort* __restrict__ out_wt, ushort* __restrict__ wf_t,
    float* __restrict__ bf_bias) {
  int idx = blockIdx.x*256 + threadIdx.x;
  if (idx < 36864) {
    int n = idx/192, k = idx%192;
    in_wt[idx] = to_bf16(in_w[k*192 + n]);
  } else if (idx < 73728) {
    int j = idx - 36864; int n = j/192, k = j%192;
    out_wt[j] = to_bf16(out_w[k*192 + n]);
  } else if (idx < 147456) {
    int j = idx - 73728; int n = j/192, k = j%192;
    float v = 0.f;
    if (n < 216)      v = off_w[k*216 + n];
    else if (n < 324) v = msk_w[k*108 + (n-216)];
    else if (n < 336) v = cfs_w[k*12  + (n-324)];
    wf_t[j] = to_bf16(v);
  }
  if (idx < 384) {
    float b = 0.f;
    if (idx < 216)      b = off_b[idx];
    else if (idx < 324) b = msk_b[idx-216];
    else if (idx < 336) b = cfs_b[idx-324];
    bf_bias[idx] = b;
  }
}

// ---------------- bf16 MFMA GEMM (optionally bf16 output) ----------------
template<int NW, int NSTORE, bool BF16OUT>
__global__ __launch_bounds__(256) void mfma_gemm(const ushort* __restrict__ A,
    const ushort* __restrict__ Wt, const float* __restrict__ bias,
    void* __restrict__ Cout_) {
  __shared__ ushort As[4*128*8];
  __shared__ ushort Bs[4*64*8];
  int pix0 = blockIdx.x * 128, n0 = blockIdx.y * 64;
  int tid = threadIdx.x;
  int wid = tid >> 6, lane = tid & 63;
  int lr = lane >> 4, lc = lane & 15;

  f32x4 acc[2][4];
  #pragma unroll
  for (int m=0;m<2;m++)
    #pragma unroll
    for (int j=0;j<4;j++) acc[m][j] = (f32x4){0.f,0.f,0.f,0.f};

  int sa0_kb = tid >> 7,        sa0_row = tid & 127;
  int sa1_kb = (tid+256) >> 7,  sa1_row = (tid+256) & 127;
  int sb_kb  = tid >> 6,        sb_n    = tid & 63;

  short8 pa0, pa1, pb;
  auto load_tile = [&](int k0) {
    pa0 = *(const short8*)&A[(size_t)(pix0 + sa0_row)*192 + k0 + sa0_kb*8];
    pa1 = *(const short8*)&A[(size_t)(pix0 + sa1_row)*192 + k0 + sa1_kb*8];
    pb  = *(const short8*)&Wt[(size_t)(n0 + sb_n)*192 + k0 + sb_kb*8];
  };
  load_tile(0);

  for (int t = 0; t < 6; t++) {
    __syncthreads();
    *(short8*)&As[(size_t)tid*8]        = pa0;
    *(short8*)&As[(size_t)(tid+256)*8]  = pa1;
    *(short8*)&Bs[(size_t)tid*8]        = pb;
    __syncthreads();
    if (t < 5) load_tile((t+1)*32);
    short8 a0 = *(const short8*)&As[(size_t)(lr*128 + wid*32 + lc)*8];
    short8 a1 = *(const short8*)&As[(size_t)(lr*128 + wid*32 + 16 + lc)*8];
    #pragma unroll
    for (int j=0;j<4;j++) {
      short8 b = *(const short8*)&Bs[(size_t)(lr*64 + j*16 + lc)*8];
      acc[0][j] = __builtin_amdgcn_mfma_f32_16x16x32_bf16(a0, b, acc[0][j], 0,0,0);
      acc[1][j] = __builtin_amdgcn_mfma_f32_16x16x32_bf16(a1, b, acc[1][j], 0,0,0);
    }
  }
  #pragma unroll
  for (int j=0;j<4;j++) {
    int col = n0 + j*16 + lc;
    if (NW != NSTORE && col >= NSTORE) continue;
    float bb = bias[col];
    #pragma unroll
    for (int m=0;m<2;m++) {
      size_t rbase = pix0 + wid*32 + m*16 + lr*4;
      #pragma unroll
      for (int r=0;r<4;r++) {
        float v = acc[m][j][r] + bb;
        if (BF16OUT) ((ushort*)Cout_)[(rbase + r)*NSTORE + col] = to_bf16(v);
        else         ((float*) Cout_)[(rbase + r)*NSTORE + col] = v;
      }
    }
  }
}

// ------- depthwise 5x5 + LN + GELU, sliding-window: block = 16-pixel row segment -------
#define SEG 16
__global__ __launch_bounds__(192) void dw_ln_gelu_kernel(const float* __restrict__ x,
    const float* __restrict__ dw_w, const float* __restrict__ dw_b,
    const float* __restrict__ ln_g, const float* __restrict__ ln_b,
    ushort* __restrict__ u_out) {
  int blk = blockIdx.x;                // ((n*HH + h)*4 + qw)
  int qw = blk & 3; int nh = blk >> 2;
  int h = nh & 63, n = nh >> 6;
  int c = threadIdx.x;
  int w0 = qw * SEG;

  float kw[25];
  #pragma unroll
  for (int t=0;t<25;t++) kw[t] = dw_w[t*C + c];

  float acc[SEG];
  float bb = dw_b[c];
  #pragma unroll
  for (int i=0;i<SEG;i++) acc[i] = bb;

  #pragma unroll
  for (int i=0;i<5;i++) {
    int hy = h + i - 2;
    if (hy < 0 || hy >= HH) continue;
    const float* rowp = &x[(((size_t)n*HH + hy)*WW)*C + c];
    #pragma unroll
    for (int wi=0; wi<SEG+4; wi++) {
      int w_in = w0 - 2 + wi;
      if (w_in < 0 || w_in >= WW) continue;
      float v = rowp[(size_t)w_in*C];
      #pragma unroll
      for (int j=0;j<5;j++) {
        int a = wi - j;
        if (a >= 0 && a < SEG) acc[a] += v * kw[i*5+j];
      }
    }
  }

  __shared__ float lds_acc[SEG][C+1];
  __shared__ float part1[SEG][12], part2[SEG][12];
  __shared__ float mu_s[SEG], rs_s[SEG];
  #pragma unroll
  for (int i=0;i<SEG;i++) lds_acc[i][c] = acc[i];
  __syncthreads();
  {
    int p = threadIdx.x & 15, chunk = threadIdx.x >> 4;
    float s1 = 0.f, s2 = 0.f;
    #pragma unroll
    for (int k=0;k<16;k++) {
      float v = lds_acc[p][chunk*16 + k];
      s1 += v; s2 += v*v;
    }
    part1[p][chunk] = s1; part2[p][chunk] = s2;
  }
  __syncthreads();
  if (threadIdx.x < SEG) {
    int p = threadIdx.x;
    float t1 = 0.f, t2 = 0.f;
    #pragma unroll
    for (int k=0;k<12;k++){ t1 += part1[p][k]; t2 += part2[p][k]; }
    float mu = t1 * (1.0f/C);
    float var = t2 * (1.0f/C) - mu*mu;
    mu_s[p] = mu; rs_s[p] = rsqrtf(var + 1e-5f);
  }
  __syncthreads();
  float gg = ln_g[c], lb = ln_b[c];
  size_t obase = ((size_t)nh*WW + w0)*C + c;
  #pragma unroll
  for (int i=0;i<SEG;i++) {
    float uv = (acc[i] - mu_s[i])*rs_s[i]*gg + lb;
    uv = 0.5f*uv*(1.0f + erff(uv*0.70710678118654752f));
    u_out[obase + (size_t)i*C] = to_bf16(uv);
  }
}

// ---------------- DCNv3 sampling + gated blend, 4 px/block, bf16 gathers ----------------
// addrs = validity-masked BYTE offsets into x_proj(bf16); wts premultiplied by msm*(1-cf).
#define SPX 4
__global__ __launch_bounds__(192) void sample_kernel(const float* __restrict__ omc,
    const ushort* __restrict__ x_proj, ushort* __restrict__ y_out) {
  int pix0 = blockIdx.x * SPX;
  int n = pix0 >> 12;                  // 4096 px per image
  int hw = pix0 & 4095; int h = hw >> 6; int w0 = hw & 63;
  int tid = threadIdx.x;
  __shared__ int   addrs[SPX*108*4];   // flat, int4 per (px,gp)
  __shared__ float wts[SPX*108*4];     // flat, float4 per (px,gp)
  __shared__ float msm[SPX][108];
  __shared__ float cfss[SPX][12];

  // B1: taps + raw bilinear wts (flat b128 stores); softmax; sigmoid
  for (int i = tid; i < SPX*108; i += 192) {
    int px = i / 108, gp = i % 108;
    int p = gp % 9;
    const float pts[3] = {-1.f, 0.f, 1.f};
    float ox = omc[(size_t)(pix0+px)*336 + 2*gp];
    float oy = omc[(size_t)(pix0+px)*336 + 2*gp + 1];
    float gx = 1.0f + (float)(w0+px) + pts[p/3] + ox;
    float gy = 1.0f + (float)h + pts[p%3] + oy;
    float x0f = floorf(gx), y0f = floorf(gy);
    float wx1 = gx - x0f, wy1 = gy - y0f;
    float wx0 = 1.f-wx1, wy0 = 1.f-wy1;
    int x0 = (int)x0f, y0 = (int)y0f;
    bool xv0 = (x0   >= 1) && (x0   <= 64);
    bool xv1 = (x0+1 >= 1) && (x0+1 <= 64);
    bool yv0 = (y0   >= 1) && (y0   <= 64);
    bool yv1 = (y0+1 >= 1) && (y0+1 <= 64);
    int base = n*HH*WW*C;               // element idx; *2 -> bf16 byte offset (max ~12.6MB)
    int4 a4;
    a4.x = (yv0&&xv0) ? (base + ((y0-1)*WW + (x0-1))*C)*2 : 0;
    a4.y = (yv0&&xv1) ? (base + ((y0-1)*WW + (x0  ))*C)*2 : 0;
    a4.z = (yv1&&xv0) ? (base + ((y0  )*WW + (x0-1))*C)*2 : 0;
    a4.w = (yv1&&xv1) ? (base + ((y0  )*WW + (x0  ))*C)*2 : 0;
    ((int4*)addrs)[i] = a4;
    float4 w4;
    w4.x = (yv0&&xv0) ? wx0*wy0 : 0.f;
    w4.y = (yv0&&xv1) ? wx1*wy0 : 0.f;
    w4.z = (yv1&&xv0) ? wx0*wy1 : 0.f;
    w4.w = (yv1&&xv1) ? wx1*wy1 : 0.f;
    ((float4*)wts)[i] = w4;
  }
  if (tid < SPX*12) {                    // softmax -> msm
    int px = tid / 12, gg = tid % 12;
    const float* mrow = &omc[(size_t)(pix0+px)*336 + 216 + gg*9];
    float m = -1e30f;
    #pragma unroll
    for (int p=0;p<P;p++) m = fmaxf(m, mrow[p]);
    float e[P]; float s = 0.f;
    #pragma unroll
    for (int p=0;p<P;p++){ e[p] = expf(mrow[p]-m); s += e[p]; }
    float inv = 1.0f/s;
    #pragma unroll
    for (int p=0;p<P;p++) msm[px][gg*9+p] = e[p]*inv;
  } else if (tid < SPX*12*2) {           // sigmoid -> cfs
    int q = tid - SPX*12;
    int px = q / 12, gg = q % 12;
    cfss[px][gg] = 1.0f/(1.0f+expf(-omc[(size_t)(pix0+px)*336 + 324 + gg]));
  }
  __syncthreads();
  // B2: premultiply msm*(1-cf) into wts
  for (int i = tid; i < SPX*108; i += 192) {
    int px = i / 108, gp = i % 108;
    float m = msm[px][gp] * (1.0f - cfss[px][gp/9 >= 12 ? 11 : gp/9]);
    f32x4 w4 = *(f32x4*)&wts[i*4];
    w4 *= m;
    *(f32x4*)&wts[i*4] = w4;
  }
  __syncthreads();
  // C: gather (bf16) + blend
  int c = tid, g = c >> 4;
  int c2 = c * 2;
  const char* xb = (const char*)x_proj;
  #pragma unroll
  for (int px = 0; px < SPX; px++) {
    float accY = 0.f;
    #pragma unroll
    for (int p=0;p<P;p++){
      int gp = g*P + p;
      int4   a4 = ((const int4*)addrs)[px*108+gp];
      float4 w4 = ((const float4*)wts)[px*108+gp];
      float v00 = bf2f(*(const ushort*)(xb + (unsigned)(a4.x + c2)));
      float v01 = bf2f(*(const ushort*)(xb + (unsigned)(a4.y + c2)));
      float v10 = bf2f(*(const ushort*)(xb + (unsigned)(a4.z + c2)));
      float v11 = bf2f(*(const ushort*)(xb + (unsigned)(a4.w + c2)));
      accY += w4.x*v00 + w4.y*v01 + w4.z*v10 + w4.w*v11;
    }
    float cf = cfss[px][g];
    float xc = bf2f(x_proj[(size_t)(pix0+px)*C + c]);
    y_out[(size_t)(pix0+px)*C + c] = to_bf16(accY + xc*cf);
  }
}

// ---------------- patch attention (3x3 softmax std) + residual, bf16 x1 ----------------
__global__ __launch_bounds__(256) void pattn_kernel(const float* __restrict__ x,
    const ushort* __restrict__ x1, float* __restrict__ out) {
  int pix = blockIdx.x*4 + (threadIdx.x>>6);
  int lane = threadIdx.x & 63;
  int n = pix / (HH*WW); int hw = pix % (HH*WW); int h = hw / WW; int w = hw % WW;
  size_t base = (size_t)pix*C;
  float cen[3];
  #pragma unroll
  for (int q=0;q<3;q++) cen[q] = bf2f(x1[base + lane + 64*q]);
  float sc[9];
  #pragma unroll
  for (int i=0;i<3;i++){
    int hy = h+i-1;
    #pragma unroll
    for (int j=0;j<3;j++){
      int wx = w+j-1;
      float a = 0.f;
      if (hy>=0 && hy<HH && wx>=0 && wx<WW){
        size_t nb = ((size_t)(n*HH+hy)*WW + wx)*C;
        #pragma unroll
        for (int q=0;q<3;q++) a += cen[q]*bf2f(x1[nb + lane + 64*q]);
      }
      sc[i*3+j]=a;
    }
  }
  #pragma unroll
  for (int k=0;k<9;k++){
    #pragma unroll
    for (int o=32;o>0;o>>=1) sc[k] += __shfl_xor(sc[k], o);
  }
  float m = sc[0];
  #pragma unroll
  for (int k=1;k<9;k++) m = fmaxf(m, sc[k]);
  float pr[9]; float s = 0.f;
  #pragma unroll
  for (int k=0;k<9;k++){ pr[k] = expf(sc[k]-m); s += pr[k]; }
  float inv = 1.0f/s;
  float mean = 0.f;
  #pragma unroll
  for (int k=0;k<9;k++){ pr[k] *= inv; mean += pr[k]; }
  mean *= (1.0f/9.0f);
  float var = 0.f;
  #pragma unroll
  for (int k=0;k<9;k++){ float d = pr[k]-mean; var += d*d; }
  float sd = sqrtf(var*(1.0f/8.0f));
  #pragma unroll
  for (int q=0;q<3;q++){
    int c = lane + 64*q;
    out[base+c] = x[base+c] + bf2f(x1[base+c])*sd;
  }
}

extern "C" void kernel_launch(void* const* d_in, const int* in_sizes, int n_in,
                              void* d_out, int out_size, void* d_ws, size_t ws_size,
                              hipStream_t stream) {
  const float* x     = (const float*)d_in[0];
  const float* dw_w  = (const float*)d_in[1];
  const float* dw_b  = (const float*)d_in[2];
  const float* ln_g  = (const float*)d_in[3];
  const float* ln_b  = (const float*)d_in[4];
  const float* off_w = (const float*)d_in[5];
  const float* off_b = (const float*)d_in[6];
  const float* msk_w = (const float*)d_in[7];
  const float* msk_b = (const float*)d_in[8];
  const float* in_w  = (const float*)d_in[9];
  const float* in_b  = (const float*)d_in[10];
  const float* out_w = (const float*)d_in[11];
  const float* out_b = (const float*)d_in[12];
  const float* cfs_w = (const float*)d_in[13];
  const float* cfs_b = (const float*)d_in[14];
  float* outp = (float*)d_out;

  float*  omc    = (float*)d_ws;                         // NPIX*336 f32
  ushort* xproj  = (ushort*)(omc + (size_t)NPIX*336);    // NPIX*192 bf16
  ushort* x_bf   = xproj + (size_t)NPIX*192;             // NPIX*192 bf16 (x, then x1)
  ushort* u_bf   = x_bf + (size_t)NPIX*192;              // NPIX*192 bf16 (u, then y2)
  ushort* in_wt  = u_bf + (size_t)NPIX*192;              // 192*192
  ushort* out_wt = in_wt + 192*192;                      // 192*192
  ushort* wf_t   = out_wt + 192*192;                     // 384*192
  float*  bfb    = (float*)(wf_t + 384*192);             // 384 f32

  cvt_kernel<<<NPIX*192/8/256, 256, 0, stream>>>(x, x_bf);
  prep_w_kernel<<<(147456+255)/256, 256, 0, stream>>>(in_w, out_w, off_w, msk_w, cfs_w,
                                                       off_b, msk_b, cfs_b,
                                                       in_wt, out_wt, wf_t, bfb);
  // x_proj (bf16) = x @ in_w + in_b
  mfma_gemm<192,192,true><<<dim3(NPIX/128, 3), 256, 0, stream>>>(x_bf, in_wt, in_b, xproj);
  // u (bf16) = GELU(LN(dwconv(x)))
  dw_ln_gelu_kernel<<<NB*HH*4, 192, 0, stream>>>(x, dw_w, dw_b, ln_g, ln_b, u_bf);
  // omc (f32) = u @ wf + bf
  mfma_gemm<384,336,false><<<dim3(NPIX/128, 6), 256, 0, stream>>>(u_bf, wf_t, bfb, omc);
  // y2 (bf16) = dcn-sample + gated blend (overwrites u)
  sample_kernel<<<NPIX/SPX, 192, 0, stream>>>(omc, xproj, u_bf);
  // x1 (bf16) = y2 @ out_w + out_b (overwrites x_bf; x_bf dead after first GEMM)
  mfma_gemm<192,192,true><<<dim3(NPIX/128, 3), 256, 0, stream>>>(u_bf, out_wt, out_b, x_bf);
  // out = x + x1 * patch_std
  pattn_kernel<<<NPIX/4, 256, 0, stream>>>(x, x_bf, outp);
}